// Round 1
// baseline (4552.371 us; speedup 1.0000x reference)
//
#include <hip/hip_runtime.h>

#define NN 20000      // nodes
#define NE 320000     // edges
#define D 64          // dim
#define R 4           // runs
#define NG 128        // graphs
#define NC 16         // classes
#define NL 4          // layers
#define MROWS (NN*R)  // 80000 rows for GEMM/BN
#define BN_EPS 1e-5f

// ---------------- zero ----------------
__global__ void k_zero(float* __restrict__ p, int n) {
    int i = blockIdx.x * 256 + threadIdx.x;
    if (i < n) p[i] = 0.0f;
}

// ---------------- init h + pool outs[0] ----------------
// h layout: node-major [NN][R][D] flat.
__global__ void k_init_pool(const float* __restrict__ x, const int* __restrict__ mask,
                            const int* __restrict__ batch, float* __restrict__ A,
                            float* __restrict__ pooled0) {
    int idx = blockIdx.x * 256 + threadIdx.x;  // over NN*16 quads
    if (idx >= NN * 16) return;
    int n = idx >> 4, q = idx & 15;
    const float4 xv = *(const float4*)(x + (size_t)n * D + q * 4);
    float4 s = make_float4(0.f, 0.f, 0.f, 0.f);
#pragma unroll
    for (int r = 0; r < R; r++) {
        bool drop = mask[r * NN + n] != 0;
        float4 v = drop ? make_float4(0.f, 0.f, 0.f, 0.f) : xv;
        *(float4*)(A + (size_t)n * (R * D) + r * D + q * 4) = v;
        s.x += v.x; s.y += v.y; s.z += v.z; s.w += v.w;
    }
    int g = batch[n];
    float* p = pooled0 + g * D + q * 4;
    atomicAdd(p + 0, 0.25f * s.x);
    atomicAdd(p + 1, 0.25f * s.y);
    atomicAdd(p + 2, 0.25f * s.z);
    atomicAdd(p + 3, 0.25f * s.w);
}

// ---------------- CSR build ----------------
__global__ void k_deg(const int* __restrict__ dst, int* __restrict__ deg) {
    int e = blockIdx.x * 256 + threadIdx.x;
    if (e < NE) atomicAdd(&deg[dst[e]], 1);
}

__global__ __launch_bounds__(1024) void k_scan(const int* __restrict__ deg,
                                               int* __restrict__ rowstart,
                                               int* __restrict__ cursor) {
    __shared__ int buf[1024];
    __shared__ int carry_s;
    if (threadIdx.x == 0) carry_s = 0;
    __syncthreads();
    for (int base = 0; base < NN; base += 1024) {
        int i = base + threadIdx.x;
        int v = (i < NN) ? deg[i] : 0;
        buf[threadIdx.x] = v;
        __syncthreads();
        for (int off = 1; off < 1024; off <<= 1) {
            int t = (threadIdx.x >= off) ? buf[threadIdx.x - off] : 0;
            __syncthreads();
            buf[threadIdx.x] += t;
            __syncthreads();
        }
        int carry = carry_s;
        int excl = carry + buf[threadIdx.x] - v;
        if (i < NN) { rowstart[i] = excl; cursor[i] = excl; }
        __syncthreads();
        if (threadIdx.x == 1023) carry_s = carry + buf[1023];
        __syncthreads();
    }
    if (threadIdx.x == 0) rowstart[NN] = carry_s;
}

__global__ void k_fill(const int* __restrict__ src, const int* __restrict__ dst,
                       int* __restrict__ cursor, int* __restrict__ esrc) {
    int e = blockIdx.x * 256 + threadIdx.x;
    if (e < NE) {
        int p = atomicAdd(&cursor[dst[e]], 1);
        esrc[p] = src[e];
    }
}

// ---------------- gather: B[n] = A[n] + sum_{s in N_in(n)} A[s] ----------------
// one wave per node; lane covers (r,f) quad: 64 lanes * float4 = 256 floats = [R][D]
__global__ __launch_bounds__(256) void k_gather(const float* __restrict__ A,
                                                float* __restrict__ B,
                                                const int* __restrict__ rowstart,
                                                const int* __restrict__ esrc) {
    int wid = (blockIdx.x * 256 + threadIdx.x) >> 6;
    int lane = threadIdx.x & 63;
    if (wid >= NN) return;
    int n = wid;
    float4 acc = *(const float4*)(A + (size_t)n * 256 + lane * 4);
    int s0 = rowstart[n], s1 = rowstart[n + 1];
    for (int k = s0; k < s1; k++) {
        int s = esrc[k];
        const float4 v = *(const float4*)(A + (size_t)s * 256 + lane * 4);
        acc.x += v.x; acc.y += v.y; acc.z += v.z; acc.w += v.w;
    }
    *(float4*)(B + (size_t)n * 256 + lane * 4) = acc;
}

// ---------------- fused GEMM (+optional input BN+ReLU) + output stats ----------------
// X:[MROWS][64] @ W:[64][64] + bias -> Y; accumulates colsum/colsumsq of Y into outStats.
template <bool APPLY_BN>
__global__ __launch_bounds__(256) void k_gemm(const float* __restrict__ X,
                                              float* __restrict__ Y,
                                              const float* __restrict__ W,
                                              const float* __restrict__ bias,
                                              const float* __restrict__ inStats,
                                              const float* __restrict__ gamma,
                                              const float* __restrict__ beta,
                                              float* __restrict__ outStats) {
    __shared__ float Xs[64][65];
    __shared__ float Ws[64][64];
    __shared__ float Bs[64];
    __shared__ float Pm[64], Pr[64], Pg[64], Pb[64];
    const int t = threadIdx.x;

    {   // stage W (4096 floats, 16/thread) — broadcast-read later, no pad needed
        const float4* Wv = (const float4*)W;
        float4* Wsv = (float4*)(&Ws[0][0]);
#pragma unroll
        for (int j = 0; j < 4; j++) Wsv[t + 256 * j] = Wv[t + 256 * j];
    }
    if (t < 64) {
        Bs[t] = bias[t];
        if (APPLY_BN) {
            float m = inStats[t] * (1.0f / MROWS);
            float var = inStats[64 + t] * (1.0f / MROWS) - m * m;
            Pm[t] = m;
            Pr[t] = rsqrtf(var + BN_EPS);
            Pg[t] = gamma[t];
            Pb[t] = beta[t];
        }
    }
    __syncthreads();

    const int m0 = blockIdx.x * 64;
    {   // stage X tile 64x64, applying BN+ReLU on the fly if requested
        int row = t >> 2, cb = (t & 3) * 16;
        const float* Xp = X + (size_t)(m0 + row) * 64 + cb;
#pragma unroll
        for (int j = 0; j < 4; j++) {
            float4 v = *(const float4*)(Xp + j * 4);
            int c = cb + j * 4;
            if (APPLY_BN) {
                v.x = fmaxf(fmaf((v.x - Pm[c + 0]) * Pr[c + 0], Pg[c + 0], Pb[c + 0]), 0.f);
                v.y = fmaxf(fmaf((v.y - Pm[c + 1]) * Pr[c + 1], Pg[c + 1], Pb[c + 1]), 0.f);
                v.z = fmaxf(fmaf((v.z - Pm[c + 2]) * Pr[c + 2], Pg[c + 2], Pb[c + 2]), 0.f);
                v.w = fmaxf(fmaf((v.w - Pm[c + 3]) * Pr[c + 3], Pg[c + 3], Pb[c + 3]), 0.f);
            }
            Xs[row][c + 0] = v.x; Xs[row][c + 1] = v.y;
            Xs[row][c + 2] = v.z; Xs[row][c + 3] = v.w;
        }
    }
    __syncthreads();

    const int row = t & 63, c0 = (t >> 6) * 16;
    float acc[16];
#pragma unroll
    for (int c = 0; c < 16; c++) acc[c] = Bs[c0 + c];
    for (int k = 0; k < 64; k++) {
        float xv = Xs[row][k];   // stride-65: (row+k)%32 banks -> conflict-free
#pragma unroll
        for (int c = 0; c < 16; c++) acc[c] = fmaf(xv, Ws[k][c0 + c], acc[c]);  // broadcast
    }

    float* Yp = Y + (size_t)(m0 + row) * 64 + c0;
#pragma unroll
    for (int j = 0; j < 4; j++)
        *(float4*)(Yp + 4 * j) = make_float4(acc[4 * j], acc[4 * j + 1], acc[4 * j + 2], acc[4 * j + 3]);

    // per-wave column sums/sumsq over the 64 rows -> atomics
#pragma unroll
    for (int c = 0; c < 16; c++) {
        float s = acc[c], q = acc[c] * acc[c];
#pragma unroll
        for (int off = 32; off > 0; off >>= 1) {
            s += __shfl_xor(s, off);
            q += __shfl_xor(q, off);
        }
        if ((t & 63) == 0) {
            atomicAdd(&outStats[c0 + c], s);
            atomicAdd(&outStats[64 + c0 + c], q);
        }
    }
}

// ---------------- BN+ReLU -> h, fused pooling into pooled[layer+1] ----------------
__global__ void k_bnrelu_pool(const float* __restrict__ Z, float* __restrict__ A,
                              const float* __restrict__ stats, const float* __restrict__ g,
                              const float* __restrict__ b, const int* __restrict__ batch,
                              float* __restrict__ pooled) {
    int idx = blockIdx.x * 256 + threadIdx.x;  // NN*16
    if (idx >= NN * 16) return;
    int n = idx >> 4, q = idx & 15;
    float mean[4], rs[4], gg[4], bb[4];
#pragma unroll
    for (int j = 0; j < 4; j++) {
        int c = q * 4 + j;
        float m = stats[c] * (1.0f / MROWS);
        float var = stats[64 + c] * (1.0f / MROWS) - m * m;
        mean[j] = m;
        rs[j] = rsqrtf(var + BN_EPS);
        gg[j] = g[c];
        bb[j] = b[c];
    }
    float4 s = make_float4(0.f, 0.f, 0.f, 0.f);
#pragma unroll
    for (int r = 0; r < R; r++) {
        float4 v = *(const float4*)(Z + (size_t)n * 256 + r * 64 + q * 4);
        v.x = fmaxf(fmaf((v.x - mean[0]) * rs[0], gg[0], bb[0]), 0.f);
        v.y = fmaxf(fmaf((v.y - mean[1]) * rs[1], gg[1], bb[1]), 0.f);
        v.z = fmaxf(fmaf((v.z - mean[2]) * rs[2], gg[2], bb[2]), 0.f);
        v.w = fmaxf(fmaf((v.w - mean[3]) * rs[3], gg[3], bb[3]), 0.f);
        *(float4*)(A + (size_t)n * 256 + r * 64 + q * 4) = v;
        s.x += v.x; s.y += v.y; s.z += v.z; s.w += v.w;
    }
    int gr = batch[n];
    float* p = pooled + gr * D + q * 4;
    atomicAdd(p + 0, 0.25f * s.x);
    atomicAdd(p + 1, 0.25f * s.y);
    atomicAdd(p + 2, 0.25f * s.z);
    atomicAdd(p + 3, 0.25f * s.w);
}

// ---------------- readout: logits + log_softmax ----------------
__global__ __launch_bounds__(256) void k_readout(const float* __restrict__ pooled,
                                                 const float* __restrict__ fcW,
                                                 const float* __restrict__ fcb,
                                                 float* __restrict__ out) {
    __shared__ float Wfs[5 * 64 * 16];
    __shared__ float logits[NG][NC];
    __shared__ float lse[NG];
    __shared__ float bsum[NC];
    for (int i = threadIdx.x; i < 5 * 64 * 16; i += 256) Wfs[i] = fcW[i];
    if (threadIdx.x < NC) {
        float s = 0.f;
#pragma unroll
        for (int i = 0; i < 5; i++) s += fcb[i * NC + threadIdx.x];
        bsum[threadIdx.x] = s;
    }
    __syncthreads();
#pragma unroll
    for (int j = 0; j < 8; j++) {
        int o = threadIdx.x + 256 * j;
        int g = o >> 4, c = o & 15;
        float acc = bsum[c];
#pragma unroll
        for (int i = 0; i < 5; i++) {
            const float* pp = pooled + i * (NG * D) + g * D;
            const float* ww = Wfs + i * (64 * 16) + c;
            for (int d = 0; d < 64; d++) acc = fmaf(pp[d], ww[d * 16], acc);
        }
        logits[g][c] = acc;
    }
    __syncthreads();
    if (threadIdx.x < NG) {
        int g = threadIdx.x;
        float mx = -3.4e38f;
#pragma unroll
        for (int c = 0; c < NC; c++) mx = fmaxf(mx, logits[g][c]);
        float se = 0.f;
#pragma unroll
        for (int c = 0; c < NC; c++) se += expf(logits[g][c] - mx);
        lse[g] = mx + logf(se);
    }
    __syncthreads();
#pragma unroll
    for (int j = 0; j < 8; j++) {
        int o = threadIdx.x + 256 * j;
        int g = o >> 4, c = o & 15;
        out[o] = logits[g][c] - lse[g];
    }
}

extern "C" void kernel_launch(void* const* d_in, const int* in_sizes, int n_in,
                              void* d_out, int out_size, void* d_ws, size_t ws_size,
                              hipStream_t stream) {
    const float* x = (const float*)d_in[0];
    const int* ei = (const int*)d_in[1];
    const int* srcp = ei;
    const int* dstp = ei + NE;
    const int* batch = (const int*)d_in[2];
    const int* mask = (const int*)d_in[3];
    const float* convW1 = (const float*)d_in[4];
    const float* convb1 = (const float*)d_in[5];
    const float* mlp_bn_g = (const float*)d_in[6];
    const float* mlp_bn_b = (const float*)d_in[7];
    const float* convW2 = (const float*)d_in[8];
    const float* convb2 = (const float*)d_in[9];
    const float* bn_g = (const float*)d_in[10];
    const float* bn_b = (const float*)d_in[11];
    const float* fcW = (const float*)d_in[12];
    const float* fcb = (const float*)d_in[13];
    float* out = (float*)d_out;

    float* wsf = (float*)d_ws;
    float* A = wsf;                       // [NN][R][D]  20.48 MB
    float* B = wsf + 5120000;             // 20.48 MB
    float* C = wsf + 10240000;            // 20.48 MB
    float* pooled = wsf + 15360000;       // [5][NG][D] 40960 f32
    float* stats = wsf + 15400960;        // [NL][2][2*64] 1024 f32
    int* deg = (int*)(wsf + 15401984);    // 20000
    int* rowstart = deg + NN;             // 20001
    int* cursor = rowstart + NN + 1;      // 20000
    int* esrc = cursor + NN;              // 320000

    // zero pooled + stats + deg (contiguous: 40960+1024+20000 dwords)
    int zn = 40960 + 1024 + NN;
    k_zero<<<(zn + 255) / 256, 256, 0, stream>>>(pooled, zn);

    k_init_pool<<<1250, 256, 0, stream>>>(x, mask, batch, A, pooled);

    k_deg<<<(NE + 255) / 256, 256, 0, stream>>>(dstp, deg);
    k_scan<<<1, 1024, 0, stream>>>(deg, rowstart, cursor);
    k_fill<<<(NE + 255) / 256, 256, 0, stream>>>(srcp, dstp, cursor, esrc);

    for (int i = 0; i < NL; i++) {
        float* st1 = stats + (i * 2 + 0) * 128;
        float* st2 = stats + (i * 2 + 1) * 128;
        k_gather<<<5000, 256, 0, stream>>>(A, B, rowstart, esrc);
        k_gemm<false><<<1250, 256, 0, stream>>>(B, C, convW1 + i * 4096, convb1 + i * 64,
                                                nullptr, nullptr, nullptr, st1);
        k_gemm<true><<<1250, 256, 0, stream>>>(C, B, convW2 + i * 4096, convb2 + i * 64,
                                               st1, mlp_bn_g + i * 64, mlp_bn_b + i * 64, st2);
        k_bnrelu_pool<<<1250, 256, 0, stream>>>(B, A, st2, bn_g + i * 64, bn_b + i * 64,
                                                batch, pooled + (i + 1) * (NG * D));
    }

    k_readout<<<1, 256, 0, stream>>>(pooled, fcW, fcb, out);
}

// Round 2
// 898.638 us; speedup vs baseline: 5.0659x; 5.0659x over previous
//
#include <hip/hip_runtime.h>

#define NN 20000      // nodes
#define NE 320000     // edges
#define D 64          // dim
#define R 4           // runs
#define NG 128        // graphs
#define NC 16         // classes
#define NL 4          // layers
#define MROWS (NN*R)  // 80000 rows for GEMM/BN
#define NBLK 1250     // GEMM grid (MROWS/64)
#define BN_EPS 1e-5f

// ---------------- zero ----------------
__global__ void k_zero(int* __restrict__ p, int n) {
    int i = blockIdx.x * 256 + threadIdx.x;
    if (i < n) p[i] = 0;
}

// ---------------- init h (dropout) ----------------
// h layout: node-major [NN][R][D] flat.
__global__ void k_init(const float* __restrict__ x, const int* __restrict__ mask,
                       float* __restrict__ A) {
    int idx = blockIdx.x * 256 + threadIdx.x;  // over NN*16 quads
    if (idx >= NN * 16) return;
    int n = idx >> 4, q = idx & 15;
    const float4 xv = *(const float4*)(x + (size_t)n * D + q * 4);
#pragma unroll
    for (int r = 0; r < R; r++) {
        bool drop = mask[r * NN + n] != 0;
        float4 v = drop ? make_float4(0.f, 0.f, 0.f, 0.f) : xv;
        *(float4*)(A + (size_t)n * (R * D) + r * D + q * 4) = v;
    }
}

// ---------------- segmented pooling: pooled[g][f] = 0.25 * sum_{n in g, r} A[n][r][f] ----
// batch is sorted; one block per graph, binary-search the node range.
__global__ __launch_bounds__(256) void k_pool(const float* __restrict__ A,
                                              const int* __restrict__ batch,
                                              float* __restrict__ pooled) {
    const int g = blockIdx.x;
    const int t = threadIdx.x;
    int lo = 0, hi = NN;
    while (lo < hi) { int mid = (lo + hi) >> 1; if (batch[mid] < g) lo = mid + 1; else hi = mid; }
    const int start = lo;
    lo = 0; hi = NN;
    while (lo < hi) { int mid = (lo + hi) >> 1; if (batch[mid] < g + 1) lo = mid + 1; else hi = mid; }
    const int end = lo;
    float acc = 0.f;
    for (int n = start; n < end; n++) acc += A[(size_t)n * 256 + t];
    __shared__ float red[256];
    red[t] = acc;
    __syncthreads();
    if (t < 64)
        pooled[g * D + t] = 0.25f * (red[t] + red[64 + t] + red[128 + t] + red[192 + t]);
}

// ---------------- CSR build ----------------
__global__ void k_deg(const int* __restrict__ dst, int* __restrict__ deg) {
    int e = blockIdx.x * 256 + threadIdx.x;
    if (e < NE) atomicAdd(&deg[dst[e]], 1);
}

__global__ __launch_bounds__(1024) void k_scan(const int* __restrict__ deg,
                                               int* __restrict__ rowstart,
                                               int* __restrict__ cursor) {
    __shared__ int buf[1024];
    __shared__ int carry_s;
    if (threadIdx.x == 0) carry_s = 0;
    __syncthreads();
    for (int base = 0; base < NN; base += 1024) {
        int i = base + threadIdx.x;
        int v = (i < NN) ? deg[i] : 0;
        buf[threadIdx.x] = v;
        __syncthreads();
        for (int off = 1; off < 1024; off <<= 1) {
            int t = (threadIdx.x >= off) ? buf[threadIdx.x - off] : 0;
            __syncthreads();
            buf[threadIdx.x] += t;
            __syncthreads();
        }
        int carry = carry_s;
        int excl = carry + buf[threadIdx.x] - v;
        if (i < NN) { rowstart[i] = excl; cursor[i] = excl; }
        __syncthreads();
        if (threadIdx.x == 1023) carry_s = carry + buf[1023];
        __syncthreads();
    }
    if (threadIdx.x == 0) rowstart[NN] = carry_s;
}

__global__ void k_fill(const int* __restrict__ src, const int* __restrict__ dst,
                       int* __restrict__ cursor, int* __restrict__ esrc) {
    int e = blockIdx.x * 256 + threadIdx.x;
    if (e < NE) {
        int p = atomicAdd(&cursor[dst[e]], 1);
        esrc[p] = src[e];
    }
}

// ---------------- gather: B[n] = A[n] + sum_{s in N_in(n)} A[s] ----------------
// one wave per node; lane covers (r,f) quad: 64 lanes * float4 = 256 floats = [R][D]
__global__ __launch_bounds__(256) void k_gather(const float* __restrict__ A,
                                                float* __restrict__ B,
                                                const int* __restrict__ rowstart,
                                                const int* __restrict__ esrc) {
    int wid = (blockIdx.x * 256 + threadIdx.x) >> 6;
    int lane = threadIdx.x & 63;
    if (wid >= NN) return;
    int n = wid;
    float4 acc = *(const float4*)(A + (size_t)n * 256 + lane * 4);
    int s0 = rowstart[n], s1 = rowstart[n + 1];
    for (int k = s0; k < s1; k++) {
        int s = esrc[k];
        const float4 v = *(const float4*)(A + (size_t)s * 256 + lane * 4);
        acc.x += v.x; acc.y += v.y; acc.z += v.z; acc.w += v.w;
    }
    *(float4*)(B + (size_t)n * 256 + lane * 4) = acc;
}

// ---------------- fused GEMM (+optional input BN+ReLU) + per-block stat partials ----
// X:[MROWS][64] @ W:[64][64] + bias -> Y; per-block colsum/colsumsq -> statPart[blk][128]
template <bool APPLY_BN>
__global__ __launch_bounds__(256) void k_gemm(const float* __restrict__ X,
                                              float* __restrict__ Y,
                                              const float* __restrict__ W,
                                              const float* __restrict__ bias,
                                              const float* __restrict__ inStats,
                                              const float* __restrict__ gamma,
                                              const float* __restrict__ beta,
                                              float* __restrict__ statPart) {
    __shared__ float Xs[64][65];
    __shared__ float Ws[64][64];
    __shared__ float Bs[64];
    __shared__ float Pm[64], Pr[64], Pg[64], Pb[64];
    const int t = threadIdx.x;

    {   // stage W (4096 floats, 16/thread) — broadcast-read later, no pad needed
        const float4* Wv = (const float4*)W;
        float4* Wsv = (float4*)(&Ws[0][0]);
#pragma unroll
        for (int j = 0; j < 4; j++) Wsv[t + 256 * j] = Wv[t + 256 * j];
    }
    if (t < 64) {
        Bs[t] = bias[t];
        if (APPLY_BN) {
            float m = inStats[t] * (1.0f / MROWS);
            float var = inStats[64 + t] * (1.0f / MROWS) - m * m;
            Pm[t] = m;
            Pr[t] = rsqrtf(var + BN_EPS);
            Pg[t] = gamma[t];
            Pb[t] = beta[t];
        }
    }
    __syncthreads();

    const int m0 = blockIdx.x * 64;
    {   // stage X tile 64x64, applying BN+ReLU on the fly if requested
        int row = t >> 2, cb = (t & 3) * 16;
        const float* Xp = X + (size_t)(m0 + row) * 64 + cb;
#pragma unroll
        for (int j = 0; j < 4; j++) {
            float4 v = *(const float4*)(Xp + j * 4);
            int c = cb + j * 4;
            if (APPLY_BN) {
                v.x = fmaxf(fmaf((v.x - Pm[c + 0]) * Pr[c + 0], Pg[c + 0], Pb[c + 0]), 0.f);
                v.y = fmaxf(fmaf((v.y - Pm[c + 1]) * Pr[c + 1], Pg[c + 1], Pb[c + 1]), 0.f);
                v.z = fmaxf(fmaf((v.z - Pm[c + 2]) * Pr[c + 2], Pg[c + 2], Pb[c + 2]), 0.f);
                v.w = fmaxf(fmaf((v.w - Pm[c + 3]) * Pr[c + 3], Pg[c + 3], Pb[c + 3]), 0.f);
            }
            Xs[row][c + 0] = v.x; Xs[row][c + 1] = v.y;
            Xs[row][c + 2] = v.z; Xs[row][c + 3] = v.w;
        }
    }
    __syncthreads();

    const int row = t & 63, c0 = (t >> 6) * 16;
    float acc[16];
#pragma unroll
    for (int c = 0; c < 16; c++) acc[c] = Bs[c0 + c];
    for (int k = 0; k < 64; k++) {
        float xv = Xs[row][k];   // stride-65: (row+k)%32 banks -> 2-way max, free
#pragma unroll
        for (int c = 0; c < 16; c++) acc[c] = fmaf(xv, Ws[k][c0 + c], acc[c]);  // broadcast
    }

    float* Yp = Y + (size_t)(m0 + row) * 64 + c0;
#pragma unroll
    for (int j = 0; j < 4; j++)
        *(float4*)(Yp + 4 * j) = make_float4(acc[4 * j], acc[4 * j + 1], acc[4 * j + 2], acc[4 * j + 3]);

    // per-wave column sums/sumsq over the 64 rows -> plain stores of block partials
    float* sp = statPart + (size_t)blockIdx.x * 128;
#pragma unroll
    for (int c = 0; c < 16; c++) {
        float s = acc[c], q = acc[c] * acc[c];
#pragma unroll
        for (int off = 32; off > 0; off >>= 1) {
            s += __shfl_xor(s, off);
            q += __shfl_xor(q, off);
        }
        if ((t & 63) == 0) {
            sp[c0 + c] = s;
            sp[64 + c0 + c] = q;
        }
    }
}

// ---------------- reduce stat partials: stats[j] = sum_p statPart[p][j] ----------------
__global__ __launch_bounds__(256) void k_statreduce(const float* __restrict__ part,
                                                    float* __restrict__ stats) {
    const int j = blockIdx.x;   // 0..127
    const int t = threadIdx.x;
    float s = 0.f;
    for (int p = t; p < NBLK; p += 256) s += part[(size_t)p * 128 + j];
#pragma unroll
    for (int off = 32; off > 0; off >>= 1) s += __shfl_xor(s, off);
    __shared__ float red[4];
    if ((t & 63) == 0) red[t >> 6] = s;
    __syncthreads();
    if (t == 0) stats[j] = red[0] + red[1] + red[2] + red[3];
}

// ---------------- BN+ReLU -> h ----------------
__global__ void k_bnrelu(const float* __restrict__ Z, float* __restrict__ A,
                         const float* __restrict__ stats, const float* __restrict__ g,
                         const float* __restrict__ b) {
    int idx = blockIdx.x * 256 + threadIdx.x;  // NN*16
    if (idx >= NN * 16) return;
    int n = idx >> 4, q = idx & 15;
    float mean[4], rs[4], gg[4], bb[4];
#pragma unroll
    for (int j = 0; j < 4; j++) {
        int c = q * 4 + j;
        float m = stats[c] * (1.0f / MROWS);
        float var = stats[64 + c] * (1.0f / MROWS) - m * m;
        mean[j] = m;
        rs[j] = rsqrtf(var + BN_EPS);
        gg[j] = g[c];
        bb[j] = b[c];
    }
#pragma unroll
    for (int r = 0; r < R; r++) {
        float4 v = *(const float4*)(Z + (size_t)n * 256 + r * 64 + q * 4);
        v.x = fmaxf(fmaf((v.x - mean[0]) * rs[0], gg[0], bb[0]), 0.f);
        v.y = fmaxf(fmaf((v.y - mean[1]) * rs[1], gg[1], bb[1]), 0.f);
        v.z = fmaxf(fmaf((v.z - mean[2]) * rs[2], gg[2], bb[2]), 0.f);
        v.w = fmaxf(fmaf((v.w - mean[3]) * rs[3], gg[3], bb[3]), 0.f);
        *(float4*)(A + (size_t)n * 256 + r * 64 + q * 4) = v;
    }
}

// ---------------- readout: logits + log_softmax ----------------
__global__ __launch_bounds__(256) void k_readout(const float* __restrict__ pooled,
                                                 const float* __restrict__ fcW,
                                                 const float* __restrict__ fcb,
                                                 float* __restrict__ out) {
    __shared__ float Wfs[5 * 64 * 16];
    __shared__ float logits[NG][NC];
    __shared__ float lse[NG];
    __shared__ float bsum[NC];
    for (int i = threadIdx.x; i < 5 * 64 * 16; i += 256) Wfs[i] = fcW[i];
    if (threadIdx.x < NC) {
        float s = 0.f;
#pragma unroll
        for (int i = 0; i < 5; i++) s += fcb[i * NC + threadIdx.x];
        bsum[threadIdx.x] = s;
    }
    __syncthreads();
#pragma unroll
    for (int j = 0; j < 8; j++) {
        int o = threadIdx.x + 256 * j;
        int g = o >> 4, c = o & 15;
        float acc = bsum[c];
#pragma unroll
        for (int i = 0; i < 5; i++) {
            const float* pp = pooled + i * (NG * D) + g * D;
            const float* ww = Wfs + i * (64 * 16) + c;
            for (int d = 0; d < 64; d++) acc = fmaf(pp[d], ww[d * 16], acc);
        }
        logits[g][c] = acc;
    }
    __syncthreads();
    if (threadIdx.x < NG) {
        int g = threadIdx.x;
        float mx = -3.4e38f;
#pragma unroll
        for (int c = 0; c < NC; c++) mx = fmaxf(mx, logits[g][c]);
        float se = 0.f;
#pragma unroll
        for (int c = 0; c < NC; c++) se += expf(logits[g][c] - mx);
        lse[g] = mx + logf(se);
    }
    __syncthreads();
#pragma unroll
    for (int j = 0; j < 8; j++) {
        int o = threadIdx.x + 256 * j;
        int g = o >> 4, c = o & 15;
        out[o] = logits[g][c] - lse[g];
    }
}

extern "C" void kernel_launch(void* const* d_in, const int* in_sizes, int n_in,
                              void* d_out, int out_size, void* d_ws, size_t ws_size,
                              hipStream_t stream) {
    const float* x = (const float*)d_in[0];
    const int* ei = (const int*)d_in[1];
    const int* srcp = ei;
    const int* dstp = ei + NE;
    const int* batch = (const int*)d_in[2];
    const int* mask = (const int*)d_in[3];
    const float* convW1 = (const float*)d_in[4];
    const float* convb1 = (const float*)d_in[5];
    const float* mlp_bn_g = (const float*)d_in[6];
    const float* mlp_bn_b = (const float*)d_in[7];
    const float* convW2 = (const float*)d_in[8];
    const float* convb2 = (const float*)d_in[9];
    const float* bn_g = (const float*)d_in[10];
    const float* bn_b = (const float*)d_in[11];
    const float* fcW = (const float*)d_in[12];
    const float* fcb = (const float*)d_in[13];
    float* out = (float*)d_out;

    float* wsf = (float*)d_ws;
    float* A = wsf;                        // [NN][R][D]  20.48 MB
    float* B = wsf + 5120000;              // 20.48 MB
    float* C = wsf + 10240000;             // 20.48 MB
    float* pooled = wsf + 15360000;        // [5][NG][D]  40960 f32
    float* stats = wsf + 15400960;         // [NL][2][128] 1024 f32
    float* statPart = wsf + 15401984;      // [NBLK][128] 160000 f32
    int* deg = (int*)(wsf + 15561984);     // 20000
    int* rowstart = deg + NN;              // 20001
    int* cursor = rowstart + NN + 1;       // 20000
    int* esrc = cursor + NN;               // 320000

    k_zero<<<(NN + 255) / 256, 256, 0, stream>>>(deg, NN);

    k_init<<<1250, 256, 0, stream>>>(x, mask, A);
    k_pool<<<NG, 256, 0, stream>>>(A, batch, pooled);

    k_deg<<<(NE + 255) / 256, 256, 0, stream>>>(dstp, deg);
    k_scan<<<1, 1024, 0, stream>>>(deg, rowstart, cursor);
    k_fill<<<(NE + 255) / 256, 256, 0, stream>>>(srcp, dstp, cursor, esrc);

    for (int i = 0; i < NL; i++) {
        float* st1 = stats + (i * 2 + 0) * 128;
        float* st2 = stats + (i * 2 + 1) * 128;
        k_gather<<<5000, 256, 0, stream>>>(A, B, rowstart, esrc);
        k_gemm<false><<<NBLK, 256, 0, stream>>>(B, C, convW1 + i * 4096, convb1 + i * 64,
                                                nullptr, nullptr, nullptr, statPart);
        k_statreduce<<<128, 256, 0, stream>>>(statPart, st1);
        k_gemm<true><<<NBLK, 256, 0, stream>>>(C, B, convW2 + i * 4096, convb2 + i * 64,
                                               st1, mlp_bn_g + i * 64, mlp_bn_b + i * 64, statPart);
        k_statreduce<<<128, 256, 0, stream>>>(statPart, st2);
        k_bnrelu<<<1250, 256, 0, stream>>>(B, A, st2, bn_g + i * 64, bn_b + i * 64);
        k_pool<<<NG, 256, 0, stream>>>(A, batch, pooled + (i + 1) * (NG * D));
    }

    k_readout<<<1, 256, 0, stream>>>(pooled, fcW, fcb, out);
}

// Round 3
// 577.266 us; speedup vs baseline: 7.8861x; 1.5567x over previous
//
#include <hip/hip_runtime.h>

typedef unsigned short u16;
typedef unsigned int u32;

#define NN 20000      // nodes
#define NE 320000     // edges
#define D 64          // dim
#define R 4           // runs
#define NG 128        // graphs
#define NC 16         // classes
#define NL 4          // layers
#define MROWS (NN*R)  // 80000 rows for GEMM/BN
#define NBLK 1250     // GEMM grid (MROWS/64)
#define BN_EPS 1e-5f

__device__ __forceinline__ float bf2f(u16 v) {
    union { u32 u; float f; } c; c.u = ((u32)v) << 16; return c.f;
}
__device__ __forceinline__ u16 f2bf(float f) {
    union { u32 u; float f; } c; c.f = f;
    u32 u = c.u;
    return (u16)((u + 0x7fffu + ((u >> 16) & 1u)) >> 16);   // RNE
}

// ---------------- zero ----------------
__global__ void k_zero(int* __restrict__ p, int n) {
    int i = blockIdx.x * 256 + threadIdx.x;
    if (i < n) p[i] = 0;
}

// ---------------- init h (dropout) -> bf16 [NN][R*D] ----------------
__global__ void k_init(const float* __restrict__ x, const int* __restrict__ mask,
                       u16* __restrict__ A) {
    int idx = blockIdx.x * 256 + threadIdx.x;  // NN*16 quads
    if (idx >= NN * 16) return;
    int n = idx >> 4, q = idx & 15;
    const float4 xv = *(const float4*)(x + (size_t)n * D + q * 4);
    ushort4 pv, zv;
    pv.x = f2bf(xv.x); pv.y = f2bf(xv.y); pv.z = f2bf(xv.z); pv.w = f2bf(xv.w);
    zv.x = zv.y = zv.z = zv.w = 0;
#pragma unroll
    for (int r = 0; r < R; r++) {
        bool drop = mask[r * NN + n] != 0;
        *(ushort4*)(A + (size_t)n * 256 + r * 64 + q * 4) = drop ? zv : pv;
    }
}

// ---------------- CSR build ----------------
__global__ void k_deg(const int* __restrict__ dst, int* __restrict__ deg) {
    int e = blockIdx.x * 256 + threadIdx.x;
    if (e < NE) atomicAdd(&deg[dst[e]], 1);
}

__global__ __launch_bounds__(1024) void k_scan(const int* __restrict__ deg,
                                               int* __restrict__ rowstart,
                                               int* __restrict__ cursor) {
    __shared__ int buf[1024];
    __shared__ int carry_s;
    if (threadIdx.x == 0) carry_s = 0;
    __syncthreads();
    for (int base = 0; base < NN; base += 1024) {
        int i = base + threadIdx.x;
        int v = (i < NN) ? deg[i] : 0;
        buf[threadIdx.x] = v;
        __syncthreads();
        for (int off = 1; off < 1024; off <<= 1) {
            int t = (threadIdx.x >= off) ? buf[threadIdx.x - off] : 0;
            __syncthreads();
            buf[threadIdx.x] += t;
            __syncthreads();
        }
        int carry = carry_s;
        int excl = carry + buf[threadIdx.x] - v;
        if (i < NN) { rowstart[i] = excl; cursor[i] = excl; }
        __syncthreads();
        if (threadIdx.x == 1023) carry_s = carry + buf[1023];
        __syncthreads();
    }
    if (threadIdx.x == 0) rowstart[NN] = carry_s;
}

__global__ void k_fill(const int* __restrict__ src, const int* __restrict__ dst,
                       int* __restrict__ cursor, int* __restrict__ esrc) {
    int e = blockIdx.x * 256 + threadIdx.x;
    if (e < NE) {
        int p = atomicAdd(&cursor[dst[e]], 1);
        esrc[p] = src[e];
    }
}

// ---------------- gather with fused BN-affine+ReLU on loads ----------------
// B[n] = f(Z[n]) + sum_{s in N_in(n)} f(Z[s]),  f = identity (layer 0) or BN+ReLU
// one wave per node; lane covers elems 4l..4l+3 of the 256-elem row (col c=(4l)&63)
template <bool APPLY>
__global__ __launch_bounds__(256) void k_gather(const u16* __restrict__ Z,
                                                u16* __restrict__ B,
                                                const int* __restrict__ rowstart,
                                                const int* __restrict__ esrc,
                                                const float* __restrict__ stats,
                                                const float* __restrict__ g,
                                                const float* __restrict__ b) {
    int wid = (blockIdx.x * 256 + threadIdx.x) >> 6;
    int lane = threadIdx.x & 63;
    if (wid >= NN) return;
    const int c0 = (lane * 4) & 63;
    float sc[4] = {1.f, 1.f, 1.f, 1.f}, sh[4] = {0.f, 0.f, 0.f, 0.f};
    if (APPLY) {
#pragma unroll
        for (int j = 0; j < 4; j++) {
            int c = c0 + j;
            float m = stats[c] * (1.0f / MROWS);
            float var = stats[64 + c] * (1.0f / MROWS) - m * m;
            float rs = rsqrtf(var + BN_EPS);
            sc[j] = g[c] * rs;
            sh[j] = b[c] - m * sc[j];
        }
    }
    float acc[4] = {0.f, 0.f, 0.f, 0.f};
    {
        ushort4 v = *(const ushort4*)(Z + (size_t)wid * 256 + lane * 4);
        float f0 = bf2f(v.x), f1 = bf2f(v.y), f2 = bf2f(v.z), f3 = bf2f(v.w);
        if (APPLY) {
            f0 = fmaxf(fmaf(f0, sc[0], sh[0]), 0.f);
            f1 = fmaxf(fmaf(f1, sc[1], sh[1]), 0.f);
            f2 = fmaxf(fmaf(f2, sc[2], sh[2]), 0.f);
            f3 = fmaxf(fmaf(f3, sc[3], sh[3]), 0.f);
        }
        acc[0] = f0; acc[1] = f1; acc[2] = f2; acc[3] = f3;
    }
    int s0 = rowstart[wid], s1 = rowstart[wid + 1];
    for (int k = s0; k < s1; k++) {
        int s = esrc[k];
        ushort4 v = *(const ushort4*)(Z + (size_t)s * 256 + lane * 4);
        float f0 = bf2f(v.x), f1 = bf2f(v.y), f2 = bf2f(v.z), f3 = bf2f(v.w);
        if (APPLY) {
            f0 = fmaxf(fmaf(f0, sc[0], sh[0]), 0.f);
            f1 = fmaxf(fmaf(f1, sc[1], sh[1]), 0.f);
            f2 = fmaxf(fmaf(f2, sc[2], sh[2]), 0.f);
            f3 = fmaxf(fmaf(f3, sc[3], sh[3]), 0.f);
        }
        acc[0] += f0; acc[1] += f1; acc[2] += f2; acc[3] += f3;
    }
    ushort4 o;
    o.x = f2bf(acc[0]); o.y = f2bf(acc[1]); o.z = f2bf(acc[2]); o.w = f2bf(acc[3]);
    *(ushort4*)(B + (size_t)wid * 256 + lane * 4) = o;
}

// ---------------- GEMM (bf16 in/out, f32 compute) + fused input BN + stat partials ----
// X:[MROWS][64] @ W:[64][64] + bias -> Y; partials to part[j][NBLK] (transposed)
template <bool APPLY>
__global__ __launch_bounds__(256) void k_gemm(const u16* __restrict__ X,
                                              u16* __restrict__ Y,
                                              const float* __restrict__ W,
                                              const float* __restrict__ bias,
                                              const float* __restrict__ inStats,
                                              const float* __restrict__ gamma,
                                              const float* __restrict__ beta,
                                              float* __restrict__ part) {
    __shared__ float Xs[64][65];
    __shared__ float Ws[64][64];
    __shared__ float Bs[64];
    __shared__ float Pm[64], Pr[64], Pg[64], Pb[64];
    const int t = threadIdx.x;

    {   // stage W (f32, 4096 floats)
        const float4* Wv = (const float4*)W;
        float4* Wsv = (float4*)(&Ws[0][0]);
#pragma unroll
        for (int j = 0; j < 4; j++) Wsv[t + 256 * j] = Wv[t + 256 * j];
    }
    if (t < 64) {
        Bs[t] = bias[t];
        if (APPLY) {
            float m = inStats[t] * (1.0f / MROWS);
            float var = inStats[64 + t] * (1.0f / MROWS) - m * m;
            Pm[t] = m;
            Pr[t] = rsqrtf(var + BN_EPS);
            Pg[t] = gamma[t];
            Pb[t] = beta[t];
        }
    }
    __syncthreads();

    const int row = t >> 2;            // 0..63
    const int c0 = (t & 3) * 16;       // col chunk
    const int m0 = blockIdx.x * 64;

    {   // stage X[row][c0..c0+15]: bf16 -> f32 (+BN+ReLU)
        const u16* Xp = X + (size_t)(m0 + row) * 64 + c0;
        uint4 a = *(const uint4*)Xp;
        uint4 bq = *(const uint4*)(Xp + 8);
        u32 w[8] = {a.x, a.y, a.z, a.w, bq.x, bq.y, bq.z, bq.w};
#pragma unroll
        for (int j = 0; j < 8; j++) {
            int c = c0 + 2 * j;
            union { u32 u; float f; } lo, hi;
            lo.u = w[j] << 16;
            hi.u = w[j] & 0xffff0000u;
            float v0 = lo.f, v1 = hi.f;
            if (APPLY) {
                v0 = fmaxf(fmaf((v0 - Pm[c]) * Pr[c], Pg[c], Pb[c]), 0.f);
                v1 = fmaxf(fmaf((v1 - Pm[c + 1]) * Pr[c + 1], Pg[c + 1], Pb[c + 1]), 0.f);
            }
            Xs[row][c] = v0;
            Xs[row][c + 1] = v1;
        }
    }
    __syncthreads();

    float acc[16];
#pragma unroll
    for (int c = 0; c < 16; c++) acc[c] = Bs[c0 + c];
    for (int k = 0; k < 64; k++) {
        float xv = Xs[row][k];
        float4 w0 = *(const float4*)&Ws[k][c0];
        float4 w1 = *(const float4*)&Ws[k][c0 + 4];
        float4 w2 = *(const float4*)&Ws[k][c0 + 8];
        float4 w3 = *(const float4*)&Ws[k][c0 + 12];
        acc[0] = fmaf(xv, w0.x, acc[0]);  acc[1] = fmaf(xv, w0.y, acc[1]);
        acc[2] = fmaf(xv, w0.z, acc[2]);  acc[3] = fmaf(xv, w0.w, acc[3]);
        acc[4] = fmaf(xv, w1.x, acc[4]);  acc[5] = fmaf(xv, w1.y, acc[5]);
        acc[6] = fmaf(xv, w1.z, acc[6]);  acc[7] = fmaf(xv, w1.w, acc[7]);
        acc[8] = fmaf(xv, w2.x, acc[8]);  acc[9] = fmaf(xv, w2.y, acc[9]);
        acc[10] = fmaf(xv, w2.z, acc[10]); acc[11] = fmaf(xv, w2.w, acc[11]);
        acc[12] = fmaf(xv, w3.x, acc[12]); acc[13] = fmaf(xv, w3.y, acc[13]);
        acc[14] = fmaf(xv, w3.z, acc[14]); acc[15] = fmaf(xv, w3.w, acc[15]);
    }

    {   // store Y as bf16 (wave-contiguous rows)
        u32 ow[8];
#pragma unroll
        for (int j = 0; j < 8; j++)
            ow[j] = (u32)f2bf(acc[2 * j]) | ((u32)f2bf(acc[2 * j + 1]) << 16);
        u16* Yp = Y + (size_t)(m0 + row) * 64 + c0;
        *(uint4*)Yp = make_uint4(ow[0], ow[1], ow[2], ow[3]);
        *(uint4*)(Yp + 8) = make_uint4(ow[4], ow[5], ow[6], ow[7]);
    }

    // column sum/sumsq over this block's 64 rows (f32 acc, pre-rounding)
    float s[16], q[16];
#pragma unroll
    for (int c = 0; c < 16; c++) { s[c] = acc[c]; q[c] = acc[c] * acc[c]; }
#pragma unroll
    for (int c = 0; c < 16; c++) {
#pragma unroll
        for (int off = 4; off < 64; off <<= 1) {   // reduce over the 16 rows in this wave
            s[c] += __shfl_xor(s[c], off);
            q[c] += __shfl_xor(q[c], off);
        }
    }
    __syncthreads();                      // Xs dead; reuse as reduction scratch
    float* red = &Xs[0][0];               // [4][256] layout
    if ((t & 63) < 4) {
        int w = t >> 6;
#pragma unroll
        for (int c = 0; c < 16; c++) {
            red[w * 256 + c0 + c] = s[c];
            red[w * 256 + 128 + c0 + c] = q[c];
        }
    }
    __syncthreads();
    if (t < 128) {
        int idx = (t < 64) ? t : (t + 64);
        float v = red[idx] + red[256 + idx] + red[512 + idx] + red[768 + idx];
        part[(size_t)t * NBLK + blockIdx.x] = v;
    }
}

// ---------------- reduce stat partials (coalesced) ----------------
__global__ __launch_bounds__(256) void k_statreduce(const float* __restrict__ part,
                                                    float* __restrict__ stats) {
    const int j = blockIdx.x;   // 0..127
    const int t = threadIdx.x;
    float s = 0.f;
    for (int p = t; p < NBLK; p += 256) s += part[(size_t)j * NBLK + p];
#pragma unroll
    for (int off = 32; off > 0; off >>= 1) s += __shfl_xor(s, off);
    __shared__ float red[4];
    if ((t & 63) == 0) red[t >> 6] = s;
    __syncthreads();
    if (t == 0) stats[j] = red[0] + red[1] + red[2] + red[3];
}

// ---------------- segmented pooling with fused BN-affine+ReLU ----------------
template <bool APPLY>
__global__ __launch_bounds__(256) void k_pool(const u16* __restrict__ Z,
                                              const int* __restrict__ batch,
                                              float* __restrict__ pooled,
                                              const float* __restrict__ stats,
                                              const float* __restrict__ g,
                                              const float* __restrict__ b) {
    const int gr = blockIdx.x;
    const int t = threadIdx.x;
    int lo = 0, hi = NN;
    while (lo < hi) { int mid = (lo + hi) >> 1; if (batch[mid] < gr) lo = mid + 1; else hi = mid; }
    const int start = lo;
    lo = 0; hi = NN;
    while (lo < hi) { int mid = (lo + hi) >> 1; if (batch[mid] < gr + 1) lo = mid + 1; else hi = mid; }
    const int end = lo;

    const int l = t & 63, w = t >> 6;
    const int c0 = (l * 4) & 63;
    float sc[4] = {1.f, 1.f, 1.f, 1.f}, sh[4] = {0.f, 0.f, 0.f, 0.f};
    if (APPLY) {
#pragma unroll
        for (int j = 0; j < 4; j++) {
            int c = c0 + j;
            float m = stats[c] * (1.0f / MROWS);
            float var = stats[64 + c] * (1.0f / MROWS) - m * m;
            float rs = rsqrtf(var + BN_EPS);
            sc[j] = g[c] * rs;
            sh[j] = b[c] - m * sc[j];
        }
    }
    float acc[4] = {0.f, 0.f, 0.f, 0.f};
    for (int n = start + w; n < end; n += 4) {
        ushort4 v = *(const ushort4*)(Z + (size_t)n * 256 + l * 4);
        float f0 = bf2f(v.x), f1 = bf2f(v.y), f2 = bf2f(v.z), f3 = bf2f(v.w);
        if (APPLY) {
            f0 = fmaxf(fmaf(f0, sc[0], sh[0]), 0.f);
            f1 = fmaxf(fmaf(f1, sc[1], sh[1]), 0.f);
            f2 = fmaxf(fmaf(f2, sc[2], sh[2]), 0.f);
            f3 = fmaxf(fmaf(f3, sc[3], sh[3]), 0.f);
        }
        acc[0] += f0; acc[1] += f1; acc[2] += f2; acc[3] += f3;
    }
    __shared__ float red[256][4];
    red[t][0] = acc[0]; red[t][1] = acc[1]; red[t][2] = acc[2]; red[t][3] = acc[3];
    __syncthreads();
    if (t < 64) {
        float s = 0.f;
#pragma unroll
        for (int w2 = 0; w2 < 4; w2++)
#pragma unroll
            for (int r = 0; r < 4; r++)
                s += red[w2 * 64 + r * 16 + (t >> 2)][t & 3];
        pooled[gr * D + t] = 0.25f * s;
    }
}

// ---------------- readout: one block per graph ----------------
__global__ __launch_bounds__(256) void k_readout(const float* __restrict__ pooled,
                                                 const float* __restrict__ fcW,
                                                 const float* __restrict__ fcb,
                                                 float* __restrict__ out) {
    const int gr = blockIdx.x, t = threadIdx.x;
    const int c = t & 15, seg = t >> 4;
    float acc = 0.f;
#pragma unroll
    for (int i = 0; i < 5; i++)
#pragma unroll
        for (int k = 0; k < 4; k++) {
            int d = seg * 4 + k;
            acc = fmaf(pooled[i * (NG * D) + gr * D + d], fcW[i * 1024 + d * 16 + c], acc);
        }
    __shared__ float red[16][17];
    red[seg][c] = acc;
    __syncthreads();
    if (t < 16) {
        float s = 0.f;
#pragma unroll
        for (int s2 = 0; s2 < 16; s2++) s += red[s2][t];
#pragma unroll
        for (int i = 0; i < 5; i++) s += fcb[i * NC + t];
        float mx = s;
#pragma unroll
        for (int m = 1; m < 16; m <<= 1) mx = fmaxf(mx, __shfl_xor(mx, m));
        float e = expf(s - mx), se = e;
#pragma unroll
        for (int m = 1; m < 16; m <<= 1) se += __shfl_xor(se, m);
        out[gr * NC + t] = s - mx - logf(se);
    }
}

extern "C" void kernel_launch(void* const* d_in, const int* in_sizes, int n_in,
                              void* d_out, int out_size, void* d_ws, size_t ws_size,
                              hipStream_t stream) {
    const float* x = (const float*)d_in[0];
    const int* ei = (const int*)d_in[1];
    const int* srcp = ei;
    const int* dstp = ei + NE;
    const int* batch = (const int*)d_in[2];
    const int* mask = (const int*)d_in[3];
    const float* convW1 = (const float*)d_in[4];
    const float* convb1 = (const float*)d_in[5];
    const float* mlp_bn_g = (const float*)d_in[6];
    const float* mlp_bn_b = (const float*)d_in[7];
    const float* convW2 = (const float*)d_in[8];
    const float* convb2 = (const float*)d_in[9];
    const float* bn_g = (const float*)d_in[10];
    const float* bn_b = (const float*)d_in[11];
    const float* fcW = (const float*)d_in[12];
    const float* fcb = (const float*)d_in[13];
    float* out = (float*)d_out;

    u16* A = (u16*)d_ws;                   // [NN][256] bf16 = 10.24 MB
    u16* P = A + (size_t)NN * 256;
    u16* Q = P + (size_t)NN * 256;
    float* pooled = (float*)(Q + (size_t)NN * 256);  // [5][NG][D]
    float* stats = pooled + 5 * NG * D;              // [NL][2][128]
    float* part = stats + NL * 2 * 128;              // [128][NBLK]
    int* deg = (int*)(part + 128 * NBLK);
    int* rowstart = deg + NN;
    int* cursor = rowstart + NN + 1;
    int* esrc = cursor + NN;

    k_zero<<<(NN + 255) / 256, 256, 0, stream>>>(deg, NN);
    k_init<<<1250, 256, 0, stream>>>(x, mask, A);
    k_pool<false><<<NG, 256, 0, stream>>>(A, batch, pooled, nullptr, nullptr, nullptr);

    k_deg<<<(NE + 255) / 256, 256, 0, stream>>>(dstp, deg);
    k_scan<<<1, 1024, 0, stream>>>(deg, rowstart, cursor);
    k_fill<<<(NE + 255) / 256, 256, 0, stream>>>(srcp, dstp, cursor, esrc);

    for (int i = 0; i < NL; i++) {
        float* st1 = stats + (i * 2 + 0) * 128;
        float* st2 = stats + (i * 2 + 1) * 128;
        u16* Zi = (i % 2 == 0) ? P : Q;
        u16* Mid = (i % 2 == 0) ? Q : P;
        const u16* Zp = (i == 0) ? A : ((i % 2 == 0) ? Q : P);
        if (i == 0)
            k_gather<false><<<5000, 256, 0, stream>>>(Zp, Zi, rowstart, esrc,
                                                      nullptr, nullptr, nullptr);
        else
            k_gather<true><<<5000, 256, 0, stream>>>(Zp, Zi, rowstart, esrc,
                                                     stats + ((i - 1) * 2 + 1) * 128,
                                                     bn_g + (i - 1) * 64, bn_b + (i - 1) * 64);
        k_gemm<false><<<NBLK, 256, 0, stream>>>(Zi, Mid, convW1 + i * 4096, convb1 + i * 64,
                                                nullptr, nullptr, nullptr, part);
        k_statreduce<<<128, 256, 0, stream>>>(part, st1);
        k_gemm<true><<<NBLK, 256, 0, stream>>>(Mid, Zi, convW2 + i * 4096, convb2 + i * 64,
                                               st1, mlp_bn_g + i * 64, mlp_bn_b + i * 64, part);
        k_statreduce<<<128, 256, 0, stream>>>(part, st2);
        k_pool<true><<<NG, 256, 0, stream>>>(Zi, batch, pooled + (i + 1) * (NG * D),
                                             st2, bn_g + i * 64, bn_b + i * 64);
    }

    k_readout<<<NG, 256, 0, stream>>>(pooled, fcW, fcb, out);
}

// Round 4
// 439.900 us; speedup vs baseline: 10.3486x; 1.3123x over previous
//
#include <hip/hip_runtime.h>

typedef unsigned short u16;
typedef unsigned int u32;

#define NN 20000      // nodes
#define NE 320000     // edges
#define D 64          // dim
#define R 4           // runs
#define NG 128        // graphs
#define NC 16         // classes
#define NL 4          // layers
#define MROWS (NN*R)  // 80000 rows for GEMM/BN
#define NBLK 1250     // GEMM grid (MROWS/64)
#define BN_EPS 1e-5f

__device__ __forceinline__ float bf2f(u16 v) {
    union { u32 u; float f; } c; c.u = ((u32)v) << 16; return c.f;
}
__device__ __forceinline__ u16 f2bf(float f) {
    union { u32 u; float f; } c; c.f = f;
    u32 u = c.u;
    return (u16)((u + 0x7fffu + ((u >> 16) & 1u)) >> 16);   // RNE
}

// ---------------- zero ----------------
__global__ void k_zero(int* __restrict__ p, int n) {
    int i = blockIdx.x * 256 + threadIdx.x;
    if (i < n) p[i] = 0;
}

// ---------------- pack drop mask: bit r = dropped in run r ----------------
__global__ void k_maskpack(const int* __restrict__ mask, u32* __restrict__ m4) {
    int n = blockIdx.x * 256 + threadIdx.x;
    if (n < NN) {
        u32 v = 0;
#pragma unroll
        for (int r = 0; r < R; r++) v |= (mask[r * NN + n] != 0 ? 1u : 0u) << r;
        m4[n] = v;
    }
}

// ---------------- pool of layer-0 activations: sum_n x[n] * kept(n)/4 ----------------
__global__ __launch_bounds__(256) void k_pool0(const float* __restrict__ x,
                                               const u32* __restrict__ m4,
                                               const int* __restrict__ batch,
                                               float* __restrict__ pooled) {
    const int gr = blockIdx.x, t = threadIdx.x;
    int lo = 0, hi = NN;
    while (lo < hi) { int mid = (lo + hi) >> 1; if (batch[mid] < gr) lo = mid + 1; else hi = mid; }
    const int start = lo;
    lo = 0; hi = NN;
    while (lo < hi) { int mid = (lo + hi) >> 1; if (batch[mid] < gr + 1) lo = mid + 1; else hi = mid; }
    const int end = lo;
    const int lane = t & 63, w = t >> 6;
    float acc = 0.f;
    int n = start + w;
    for (; n + 12 < end; n += 16) {
#pragma unroll
        for (int j = 0; j < 4; j++) {
            int nn = n + 4 * j;
            float wn = 0.25f * (float)(4 - __popc(m4[nn] & 0xFu));
            acc += x[(size_t)nn * 64 + lane] * wn;
        }
    }
    for (; n < end; n += 4) {
        float wn = 0.25f * (float)(4 - __popc(m4[n] & 0xFu));
        acc += x[(size_t)n * 64 + lane] * wn;
    }
    __shared__ float red[4][64];
    red[w][lane] = acc;
    __syncthreads();
    if (t < 64) pooled[gr * 64 + t] = red[0][t] + red[1][t] + red[2][t] + red[3][t];
}

// ---------------- CSR build ----------------
__global__ void k_deg(const int* __restrict__ dst, int* __restrict__ deg) {
    int e = blockIdx.x * 256 + threadIdx.x;
    if (e < NE) atomicAdd(&deg[dst[e]], 1);
}

__global__ __launch_bounds__(1024) void k_scan(const int* __restrict__ deg,
                                               int* __restrict__ rowstart,
                                               int* __restrict__ cursor) {
    __shared__ int wsum[16];
    __shared__ int woff[16];
    __shared__ int carry_s, chunktot;
    const int t = threadIdx.x, lane = t & 63, wv = t >> 6;
    if (t == 0) carry_s = 0;
    __syncthreads();
    for (int base = 0; base < NN; base += 1024) {
        int i = base + t;
        int v = (i < NN) ? deg[i] : 0;
        int x = v;
#pragma unroll
        for (int off = 1; off < 64; off <<= 1) {
            int y = __shfl_up(x, off);
            if (lane >= off) x += y;
        }
        if (lane == 63) wsum[wv] = x;
        __syncthreads();
        if (t < 16) {
            int s = wsum[t], sx = s;
#pragma unroll
            for (int off = 1; off < 16; off <<= 1) {
                int y = __shfl_up(sx, off);
                if (t >= off) sx += y;
            }
            woff[t] = sx - s;
            if (t == 15) chunktot = sx;
        }
        __syncthreads();
        int excl = carry_s + woff[wv] + x - v;
        if (i < NN) { rowstart[i] = excl; cursor[i] = excl; }
        __syncthreads();
        if (t == 0) carry_s += chunktot;
        __syncthreads();
    }
    if (t == 0) rowstart[NN] = carry_s;
}

__global__ void k_fill(const int* __restrict__ src, const int* __restrict__ dst,
                       int* __restrict__ cursor, int* __restrict__ esrc) {
    int e = blockIdx.x * 256 + threadIdx.x;
    if (e < NE) {
        int p = atomicAdd(&cursor[dst[e]], 1);
        esrc[p] = src[e];
    }
}

// ---------------- fused gather(+BN)+GEMM1+stat partials ----------------
// FIRST: input = f32 x + packed drop mask (layer 0). else: bf16 Z + BN-affine+ReLU.
// Block = 16 nodes = 64 GEMM rows; wave w gathers nodes blk*16+4w..+3 into LDS.
template <bool FIRST>
__global__ __launch_bounds__(256) void k_fgg(const u16* __restrict__ Z,
                                             const float* __restrict__ x,
                                             const u32* __restrict__ m4,
                                             u16* __restrict__ Y,
                                             const int* __restrict__ rowstart,
                                             const int* __restrict__ esrc,
                                             const float* __restrict__ stats,
                                             const float* __restrict__ g,
                                             const float* __restrict__ b,
                                             const float* __restrict__ W,
                                             const float* __restrict__ bias,
                                             float* __restrict__ part) {
    __shared__ float Xs[64][65];
    __shared__ float Ws[64][64];
    __shared__ float Bs[64];
    const int t = threadIdx.x;
    const int lane = t & 63, wv = t >> 6;

    {   // stage W (f32, 4096 floats)
        const float4* Wv4 = (const float4*)W;
        float4* Wsv = (float4*)(&Ws[0][0]);
#pragma unroll
        for (int j = 0; j < 4; j++) Wsv[t + 256 * j] = Wv4[t + 256 * j];
    }
    if (t < 64) Bs[t] = bias[t];

    const int rr = lane >> 4;          // run
    const int cl = (lane & 15) * 4;    // col base
    float sc[4] = {1.f, 1.f, 1.f, 1.f}, sh[4] = {0.f, 0.f, 0.f, 0.f};
    if (!FIRST) {
#pragma unroll
        for (int j = 0; j < 4; j++) {
            int c = cl + j;
            float m = stats[c] * (1.0f / MROWS);
            float var = stats[64 + c] * (1.0f / MROWS) - m * m;
            float rs = rsqrtf(var + BN_EPS);
            sc[j] = g[c] * rs;
            sh[j] = b[c] - m * sc[j];
        }
    }

#define LOADF(e, a0, a1, a2, a3)                                               \
    if (FIRST) {                                                               \
        u32 mb = m4[e];                                                        \
        float4 v = *(const float4*)(x + (size_t)(e) * 64 + cl);                \
        bool keep = ((mb >> rr) & 1u) == 0u;                                   \
        a0 = keep ? v.x : 0.f; a1 = keep ? v.y : 0.f;                          \
        a2 = keep ? v.z : 0.f; a3 = keep ? v.w : 0.f;                          \
    } else {                                                                   \
        ushort4 v = *(const ushort4*)(Z + (size_t)(e) * 256 + lane * 4);       \
        a0 = fmaxf(fmaf(bf2f(v.x), sc[0], sh[0]), 0.f);                        \
        a1 = fmaxf(fmaf(bf2f(v.y), sc[1], sh[1]), 0.f);                        \
        a2 = fmaxf(fmaf(bf2f(v.z), sc[2], sh[2]), 0.f);                        \
        a3 = fmaxf(fmaf(bf2f(v.w), sc[3], sh[3]), 0.f);                        \
    }

    const int n0 = blockIdx.x * 16 + wv * 4;
#pragma unroll
    for (int i = 0; i < 4; i++) {
        const int n = n0 + i;
        float a0, a1, a2, a3;
        LOADF(n, a0, a1, a2, a3);
        int s0 = __builtin_amdgcn_readfirstlane(rowstart[n]);
        int s1 = __builtin_amdgcn_readfirstlane(rowstart[n + 1]);
        int k = s0;
        for (; k + 8 <= s1; k += 8) {
            int e0 = esrc[k], e1 = esrc[k + 1], e2 = esrc[k + 2], e3 = esrc[k + 3];
            int e4 = esrc[k + 4], e5 = esrc[k + 5], e6 = esrc[k + 6], e7 = esrc[k + 7];
            float b0, b1, b2, b3;
            LOADF(e0, b0, b1, b2, b3); a0 += b0; a1 += b1; a2 += b2; a3 += b3;
            LOADF(e1, b0, b1, b2, b3); a0 += b0; a1 += b1; a2 += b2; a3 += b3;
            LOADF(e2, b0, b1, b2, b3); a0 += b0; a1 += b1; a2 += b2; a3 += b3;
            LOADF(e3, b0, b1, b2, b3); a0 += b0; a1 += b1; a2 += b2; a3 += b3;
            LOADF(e4, b0, b1, b2, b3); a0 += b0; a1 += b1; a2 += b2; a3 += b3;
            LOADF(e5, b0, b1, b2, b3); a0 += b0; a1 += b1; a2 += b2; a3 += b3;
            LOADF(e6, b0, b1, b2, b3); a0 += b0; a1 += b1; a2 += b2; a3 += b3;
            LOADF(e7, b0, b1, b2, b3); a0 += b0; a1 += b1; a2 += b2; a3 += b3;
        }
        for (; k < s1; k++) {
            int e = esrc[k];
            float b0, b1, b2, b3;
            LOADF(e, b0, b1, b2, b3); a0 += b0; a1 += b1; a2 += b2; a3 += b3;
        }
        const int lrow = (wv * 4 + i) * 4 + rr;
        Xs[lrow][cl + 0] = a0; Xs[lrow][cl + 1] = a1;
        Xs[lrow][cl + 2] = a2; Xs[lrow][cl + 3] = a3;
    }
#undef LOADF
    __syncthreads();

    // GEMM: 64x64 tile @ W
    const int row = t >> 2;
    const int c0 = (t & 3) * 16;
    float acc[16];
#pragma unroll
    for (int c = 0; c < 16; c++) acc[c] = Bs[c0 + c];
    for (int k = 0; k < 64; k++) {
        float xv = Xs[row][k];
        float4 w0 = *(const float4*)&Ws[k][c0];
        float4 w1 = *(const float4*)&Ws[k][c0 + 4];
        float4 w2 = *(const float4*)&Ws[k][c0 + 8];
        float4 w3 = *(const float4*)&Ws[k][c0 + 12];
        acc[0] = fmaf(xv, w0.x, acc[0]);  acc[1] = fmaf(xv, w0.y, acc[1]);
        acc[2] = fmaf(xv, w0.z, acc[2]);  acc[3] = fmaf(xv, w0.w, acc[3]);
        acc[4] = fmaf(xv, w1.x, acc[4]);  acc[5] = fmaf(xv, w1.y, acc[5]);
        acc[6] = fmaf(xv, w1.z, acc[6]);  acc[7] = fmaf(xv, w1.w, acc[7]);
        acc[8] = fmaf(xv, w2.x, acc[8]);  acc[9] = fmaf(xv, w2.y, acc[9]);
        acc[10] = fmaf(xv, w2.z, acc[10]); acc[11] = fmaf(xv, w2.w, acc[11]);
        acc[12] = fmaf(xv, w3.x, acc[12]); acc[13] = fmaf(xv, w3.y, acc[13]);
        acc[14] = fmaf(xv, w3.z, acc[14]); acc[15] = fmaf(xv, w3.w, acc[15]);
    }

    {   // store Y bf16
        u32 ow[8];
#pragma unroll
        for (int j = 0; j < 8; j++)
            ow[j] = (u32)f2bf(acc[2 * j]) | ((u32)f2bf(acc[2 * j + 1]) << 16);
        u16* Yp = Y + (size_t)(blockIdx.x * 64 + row) * 64 + c0;
        *(uint4*)Yp = make_uint4(ow[0], ow[1], ow[2], ow[3]);
        *(uint4*)(Yp + 8) = make_uint4(ow[4], ow[5], ow[6], ow[7]);
    }

    // column sum/sumsq partials
    float s[16], q[16];
#pragma unroll
    for (int c = 0; c < 16; c++) { s[c] = acc[c]; q[c] = acc[c] * acc[c]; }
#pragma unroll
    for (int c = 0; c < 16; c++) {
#pragma unroll
        for (int off = 4; off < 64; off <<= 1) {
            s[c] += __shfl_xor(s[c], off);
            q[c] += __shfl_xor(q[c], off);
        }
    }
    __syncthreads();
    float* red = &Xs[0][0];
    if ((t & 63) < 4) {
        int w = t >> 6;
#pragma unroll
        for (int c = 0; c < 16; c++) {
            red[w * 256 + c0 + c] = s[c];
            red[w * 256 + 128 + c0 + c] = q[c];
        }
    }
    __syncthreads();
    if (t < 128) {
        int idx = (t < 64) ? t : (t + 64);
        float v = red[idx] + red[256 + idx] + red[512 + idx] + red[768 + idx];
        part[(size_t)t * NBLK + blockIdx.x] = v;
    }
}

// ---------------- GEMM2 (bf16 in/out, f32 compute) + input BN + stat partials ----
__global__ __launch_bounds__(256) void k_gemm(const u16* __restrict__ X,
                                              u16* __restrict__ Y,
                                              const float* __restrict__ W,
                                              const float* __restrict__ bias,
                                              const float* __restrict__ inStats,
                                              const float* __restrict__ gamma,
                                              const float* __restrict__ beta,
                                              float* __restrict__ part) {
    __shared__ float Xs[64][65];
    __shared__ float Ws[64][64];
    __shared__ float Bs[64];
    __shared__ float Pm[64], Pr[64], Pg[64], Pb[64];
    const int t = threadIdx.x;

    {
        const float4* Wv = (const float4*)W;
        float4* Wsv = (float4*)(&Ws[0][0]);
#pragma unroll
        for (int j = 0; j < 4; j++) Wsv[t + 256 * j] = Wv[t + 256 * j];
    }
    if (t < 64) {
        Bs[t] = bias[t];
        float m = inStats[t] * (1.0f / MROWS);
        float var = inStats[64 + t] * (1.0f / MROWS) - m * m;
        Pm[t] = m;
        Pr[t] = rsqrtf(var + BN_EPS);
        Pg[t] = gamma[t];
        Pb[t] = beta[t];
    }
    __syncthreads();

    const int row = t >> 2;
    const int c0 = (t & 3) * 16;
    const int m0 = blockIdx.x * 64;

    {
        const u16* Xp = X + (size_t)(m0 + row) * 64 + c0;
        uint4 a = *(const uint4*)Xp;
        uint4 bq = *(const uint4*)(Xp + 8);
        u32 w[8] = {a.x, a.y, a.z, a.w, bq.x, bq.y, bq.z, bq.w};
#pragma unroll
        for (int j = 0; j < 8; j++) {
            int c = c0 + 2 * j;
            union { u32 u; float f; } lo, hi;
            lo.u = w[j] << 16;
            hi.u = w[j] & 0xffff0000u;
            float v0 = fmaxf(fmaf((lo.f - Pm[c]) * Pr[c], Pg[c], Pb[c]), 0.f);
            float v1 = fmaxf(fmaf((hi.f - Pm[c + 1]) * Pr[c + 1], Pg[c + 1], Pb[c + 1]), 0.f);
            Xs[row][c] = v0;
            Xs[row][c + 1] = v1;
        }
    }
    __syncthreads();

    float acc[16];
#pragma unroll
    for (int c = 0; c < 16; c++) acc[c] = Bs[c0 + c];
    for (int k = 0; k < 64; k++) {
        float xv = Xs[row][k];
        float4 w0 = *(const float4*)&Ws[k][c0];
        float4 w1 = *(const float4*)&Ws[k][c0 + 4];
        float4 w2 = *(const float4*)&Ws[k][c0 + 8];
        float4 w3 = *(const float4*)&Ws[k][c0 + 12];
        acc[0] = fmaf(xv, w0.x, acc[0]);  acc[1] = fmaf(xv, w0.y, acc[1]);
        acc[2] = fmaf(xv, w0.z, acc[2]);  acc[3] = fmaf(xv, w0.w, acc[3]);
        acc[4] = fmaf(xv, w1.x, acc[4]);  acc[5] = fmaf(xv, w1.y, acc[5]);
        acc[6] = fmaf(xv, w1.z, acc[6]);  acc[7] = fmaf(xv, w1.w, acc[7]);
        acc[8] = fmaf(xv, w2.x, acc[8]);  acc[9] = fmaf(xv, w2.y, acc[9]);
        acc[10] = fmaf(xv, w2.z, acc[10]); acc[11] = fmaf(xv, w2.w, acc[11]);
        acc[12] = fmaf(xv, w3.x, acc[12]); acc[13] = fmaf(xv, w3.y, acc[13]);
        acc[14] = fmaf(xv, w3.z, acc[14]); acc[15] = fmaf(xv, w3.w, acc[15]);
    }

    {
        u32 ow[8];
#pragma unroll
        for (int j = 0; j < 8; j++)
            ow[j] = (u32)f2bf(acc[2 * j]) | ((u32)f2bf(acc[2 * j + 1]) << 16);
        u16* Yp = Y + (size_t)(m0 + row) * 64 + c0;
        *(uint4*)Yp = make_uint4(ow[0], ow[1], ow[2], ow[3]);
        *(uint4*)(Yp + 8) = make_uint4(ow[4], ow[5], ow[6], ow[7]);
    }

    float s[16], q[16];
#pragma unroll
    for (int c = 0; c < 16; c++) { s[c] = acc[c]; q[c] = acc[c] * acc[c]; }
#pragma unroll
    for (int c = 0; c < 16; c++) {
#pragma unroll
        for (int off = 4; off < 64; off <<= 1) {
            s[c] += __shfl_xor(s[c], off);
            q[c] += __shfl_xor(q[c], off);
        }
    }
    __syncthreads();
    float* red = &Xs[0][0];
    if ((t & 63) < 4) {
        int w = t >> 6;
#pragma unroll
        for (int c = 0; c < 16; c++) {
            red[w * 256 + c0 + c] = s[c];
            red[w * 256 + 128 + c0 + c] = q[c];
        }
    }
    __syncthreads();
    if (t < 128) {
        int idx = (t < 64) ? t : (t + 64);
        float v = red[idx] + red[256 + idx] + red[512 + idx] + red[768 + idx];
        part[(size_t)t * NBLK + blockIdx.x] = v;
    }
}

// ---------------- reduce stat partials (coalesced) ----------------
__global__ __launch_bounds__(256) void k_statreduce(const float* __restrict__ part,
                                                    float* __restrict__ stats) {
    const int j = blockIdx.x;
    const int t = threadIdx.x;
    float s = 0.f;
    for (int p = t; p < NBLK; p += 256) s += part[(size_t)j * NBLK + p];
#pragma unroll
    for (int off = 32; off > 0; off >>= 1) s += __shfl_xor(s, off);
    __shared__ float red[4];
    if ((t & 63) == 0) red[t >> 6] = s;
    __syncthreads();
    if (t == 0) stats[j] = red[0] + red[1] + red[2] + red[3];
}

// ---------------- segmented pooling with fused BN-affine+ReLU ----------------
__global__ __launch_bounds__(256) void k_pool(const u16* __restrict__ Z,
                                              const int* __restrict__ batch,
                                              float* __restrict__ pooled,
                                              const float* __restrict__ stats,
                                              const float* __restrict__ g,
                                              const float* __restrict__ b) {
    const int gr = blockIdx.x;
    const int t = threadIdx.x;
    int lo = 0, hi = NN;
    while (lo < hi) { int mid = (lo + hi) >> 1; if (batch[mid] < gr) lo = mid + 1; else hi = mid; }
    const int start = lo;
    lo = 0; hi = NN;
    while (lo < hi) { int mid = (lo + hi) >> 1; if (batch[mid] < gr + 1) lo = mid + 1; else hi = mid; }
    const int end = lo;

    const int l = t & 63, w = t >> 6;
    const int c0 = (l * 4) & 63;
    float sc[4], sh[4];
#pragma unroll
    for (int j = 0; j < 4; j++) {
        int c = c0 + j;
        float m = stats[c] * (1.0f / MROWS);
        float var = stats[64 + c] * (1.0f / MROWS) - m * m;
        float rs = rsqrtf(var + BN_EPS);
        sc[j] = g[c] * rs;
        sh[j] = b[c] - m * sc[j];
    }
    float a0 = 0.f, a1 = 0.f, a2 = 0.f, a3 = 0.f;
#define PBODY(nn)                                                              \
    {                                                                          \
        ushort4 v = *(const ushort4*)(Z + (size_t)(nn) * 256 + l * 4);         \
        a0 += fmaxf(fmaf(bf2f(v.x), sc[0], sh[0]), 0.f);                       \
        a1 += fmaxf(fmaf(bf2f(v.y), sc[1], sh[1]), 0.f);                       \
        a2 += fmaxf(fmaf(bf2f(v.z), sc[2], sh[2]), 0.f);                       \
        a3 += fmaxf(fmaf(bf2f(v.w), sc[3], sh[3]), 0.f);                       \
    }
    int n = start + w;
    for (; n + 12 < end; n += 16) { PBODY(n); PBODY(n + 4); PBODY(n + 8); PBODY(n + 12); }
    for (; n < end; n += 4) PBODY(n);
#undef PBODY
    __shared__ float red[256][4];
    red[t][0] = a0; red[t][1] = a1; red[t][2] = a2; red[t][3] = a3;
    __syncthreads();
    if (t < 64) {
        float s = 0.f;
#pragma unroll
        for (int w2 = 0; w2 < 4; w2++)
#pragma unroll
            for (int r = 0; r < 4; r++)
                s += red[w2 * 64 + r * 16 + (t >> 2)][t & 3];
        pooled[gr * D + t] = 0.25f * s;
    }
}

// ---------------- readout: one block per graph ----------------
__global__ __launch_bounds__(256) void k_readout(const float* __restrict__ pooled,
                                                 const float* __restrict__ fcW,
                                                 const float* __restrict__ fcb,
                                                 float* __restrict__ out) {
    const int gr = blockIdx.x, t = threadIdx.x;
    const int c = t & 15, seg = t >> 4;
    float acc = 0.f;
#pragma unroll
    for (int i = 0; i < 5; i++)
#pragma unroll
        for (int k = 0; k < 4; k++) {
            int d = seg * 4 + k;
            acc = fmaf(pooled[i * (NG * D) + gr * D + d], fcW[i * 1024 + d * 16 + c], acc);
        }
    __shared__ float red[16][17];
    red[seg][c] = acc;
    __syncthreads();
    if (t < 16) {
        float s = 0.f;
#pragma unroll
        for (int s2 = 0; s2 < 16; s2++) s += red[s2][t];
#pragma unroll
        for (int i = 0; i < 5; i++) s += fcb[i * NC + t];
        float mx = s;
#pragma unroll
        for (int m = 1; m < 16; m <<= 1) mx = fmaxf(mx, __shfl_xor(mx, m));
        float e = expf(s - mx), se = e;
#pragma unroll
        for (int m = 1; m < 16; m <<= 1) se += __shfl_xor(se, m);
        out[gr * NC + t] = s - mx - logf(se);
    }
}

extern "C" void kernel_launch(void* const* d_in, const int* in_sizes, int n_in,
                              void* d_out, int out_size, void* d_ws, size_t ws_size,
                              hipStream_t stream) {
    const float* x = (const float*)d_in[0];
    const int* ei = (const int*)d_in[1];
    const int* srcp = ei;
    const int* dstp = ei + NE;
    const int* batch = (const int*)d_in[2];
    const int* mask = (const int*)d_in[3];
    const float* convW1 = (const float*)d_in[4];
    const float* convb1 = (const float*)d_in[5];
    const float* mlp_bn_g = (const float*)d_in[6];
    const float* mlp_bn_b = (const float*)d_in[7];
    const float* convW2 = (const float*)d_in[8];
    const float* convb2 = (const float*)d_in[9];
    const float* bn_g = (const float*)d_in[10];
    const float* bn_b = (const float*)d_in[11];
    const float* fcW = (const float*)d_in[12];
    const float* fcb = (const float*)d_in[13];
    float* out = (float*)d_out;

    u16* P = (u16*)d_ws;                             // [NN][256] bf16 (GEMM1 out)
    u16* Q = P + (size_t)NN * 256;                   // [NN][256] bf16 (layer out Z)
    float* pooled = (float*)(Q + (size_t)NN * 256);  // [5][NG][D]
    float* stats = pooled + 5 * NG * D;              // [NL][2][128]
    float* part = stats + NL * 2 * 128;              // [128][NBLK]
    u32* m4 = (u32*)(part + 128 * NBLK);             // [NN]
    int* deg = (int*)(m4 + NN);
    int* rowstart = deg + NN;
    int* cursor = rowstart + NN + 1;
    int* esrc = cursor + NN;

    k_zero<<<(NN + 255) / 256, 256, 0, stream>>>(deg, NN);
    k_maskpack<<<(NN + 255) / 256, 256, 0, stream>>>(mask, m4);
    k_pool0<<<NG, 256, 0, stream>>>(x, m4, batch, pooled);

    k_deg<<<(NE + 255) / 256, 256, 0, stream>>>(dstp, deg);
    k_scan<<<1, 1024, 0, stream>>>(deg, rowstart, cursor);
    k_fill<<<(NE + 255) / 256, 256, 0, stream>>>(srcp, dstp, cursor, esrc);

    for (int i = 0; i < NL; i++) {
        float* st1 = stats + (i * 2 + 0) * 128;
        float* st2 = stats + (i * 2 + 1) * 128;
        if (i == 0)
            k_fgg<true><<<NBLK, 256, 0, stream>>>(nullptr, x, m4, P, rowstart, esrc,
                                                  nullptr, nullptr, nullptr,
                                                  convW1, convb1, part);
        else
            k_fgg<false><<<NBLK, 256, 0, stream>>>(Q, nullptr, nullptr, P, rowstart, esrc,
                                                   stats + ((i - 1) * 2 + 1) * 128,
                                                   bn_g + (i - 1) * 64, bn_b + (i - 1) * 64,
                                                   convW1 + i * 4096, convb1 + i * 64, part);
        k_statreduce<<<128, 256, 0, stream>>>(part, st1);
        k_gemm<<<NBLK, 256, 0, stream>>>(P, Q, convW2 + i * 4096, convb2 + i * 64,
                                         st1, mlp_bn_g + i * 64, mlp_bn_b + i * 64, part);
        k_statreduce<<<128, 256, 0, stream>>>(part, st2);
        k_pool<<<NG, 256, 0, stream>>>(Q, batch, pooled + (i + 1) * (NG * D),
                                       st2, bn_g + i * 64, bn_b + i * 64);
    }

    k_readout<<<NG, 256, 0, stream>>>(pooled, fcW, fcb, out);
}

// Round 5
// 403.133 us; speedup vs baseline: 11.2925x; 1.0912x over previous
//
#include <hip/hip_runtime.h>

typedef unsigned short u16;
typedef unsigned int u32;
typedef __attribute__((ext_vector_type(8))) short bf16x8;
typedef __attribute__((ext_vector_type(4))) float f32x4;

#define NN 20000      // nodes
#define NE 320000     // edges
#define D 64          // dim
#define R 4           // runs
#define NG 128        // graphs
#define NC 16         // classes
#define NL 4          // layers
#define MROWS (NN*R)  // 80000 rows for GEMM/BN
#define NBLK 1250     // GEMM grid (MROWS/64)
#define EPAD 460000   // max padded edge slots (NE + NN*7)
#define BN_EPS 1e-5f

__device__ __forceinline__ float bf2f(u16 v) {
    union { u32 u; float f; } c; c.u = ((u32)v) << 16; return c.f;
}
__device__ __forceinline__ u16 f2bf(float f) {
    union { u32 u; float f; } c; c.f = f;
    u32 u = c.u;
    return (u16)((u + 0x7fffu + ((u >> 16) & 1u)) >> 16);   // RNE
}
// swizzled u16 index into a [64][64] bf16 LDS tile: byte = row*128 + (kbyte ^ ((row&7)<<4))
__device__ __forceinline__ int swz(int row, int kbyte) {
    return row * 64 + (((kbyte) ^ ((row & 7) << 4)) >> 1);
}

// ---------------- zero ----------------
__global__ void k_zero(int* __restrict__ p, int n) {
    int i = blockIdx.x * 256 + threadIdx.x;
    if (i < n) p[i] = 0;
}

// ---------------- pack drop mask (NN+1 entries, m4[NN]=0) ----------------
__global__ void k_maskpack(const int* __restrict__ mask, u32* __restrict__ m4) {
    int n = blockIdx.x * 256 + threadIdx.x;
    if (n <= NN) {
        u32 v = 0;
        if (n < NN) {
#pragma unroll
            for (int r = 0; r < R; r++) v |= (mask[r * NN + n] != 0 ? 1u : 0u) << r;
        }
        m4[n] = v;
    }
}

// ---------------- xb = bf16(x), padded with zero row NN ----------------
__global__ void k_prep(const float* __restrict__ x, u16* __restrict__ xb) {
    int idx = blockIdx.x * 256 + threadIdx.x;  // (NN+1)*16 quads
    if (idx >= (NN + 1) * 16) return;
    int n = idx >> 4, q = idx & 15;
    ushort4 o;
    if (n < NN) {
        float4 v = *(const float4*)(x + (size_t)n * 64 + q * 4);
        o.x = f2bf(v.x); o.y = f2bf(v.y); o.z = f2bf(v.z); o.w = f2bf(v.w);
    } else {
        o.x = o.y = o.z = o.w = 0;
    }
    *(ushort4*)(xb + (size_t)n * 64 + q * 4) = o;
}

// ---------------- pool of layer-0: sum_n x[n] * kept(n)/4 ----------------
__global__ __launch_bounds__(256) void k_pool0(const float* __restrict__ x,
                                               const u32* __restrict__ m4,
                                               const int* __restrict__ batch,
                                               float* __restrict__ pooled) {
    const int gr = blockIdx.x, t = threadIdx.x;
    int lo = 0, hi = NN;
    while (lo < hi) { int mid = (lo + hi) >> 1; if (batch[mid] < gr) lo = mid + 1; else hi = mid; }
    const int start = lo;
    lo = 0; hi = NN;
    while (lo < hi) { int mid = (lo + hi) >> 1; if (batch[mid] < gr + 1) lo = mid + 1; else hi = mid; }
    const int end = lo;
    const int lane = t & 63, w = t >> 6;
    float acc = 0.f;
    for (int n = start + w; n < end; n += 4) {
        float wn = 0.25f * (float)(4 - __popc(m4[n] & 0xFu));
        acc += x[(size_t)n * 64 + lane] * wn;
    }
    __shared__ float red[4][64];
    red[w][lane] = acc;
    __syncthreads();
    if (t < 64) pooled[gr * 64 + t] = red[0][t] + red[1][t] + red[2][t] + red[3][t];
}

// ---------------- CSR build (degrees padded to multiple of 8) ----------------
__global__ void k_deg(const int* __restrict__ dst, int* __restrict__ deg) {
    int e = blockIdx.x * 256 + threadIdx.x;
    if (e < NE) atomicAdd(&deg[dst[e]], 1);
}

__global__ __launch_bounds__(1024) void k_scan(const int* __restrict__ deg,
                                               int* __restrict__ rowstart,
                                               int* __restrict__ cursor) {
    __shared__ int wsum[16];
    __shared__ int woff[16];
    __shared__ int carry_s, chunktot;
    const int t = threadIdx.x, lane = t & 63, wv = t >> 6;
    if (t == 0) carry_s = 0;
    __syncthreads();
    for (int base = 0; base < NN; base += 1024) {
        int i = base + t;
        int v = (i < NN) ? ((deg[i] + 7) & ~7) : 0;   // padded degree
        int x = v;
#pragma unroll
        for (int off = 1; off < 64; off <<= 1) {
            int y = __shfl_up(x, off);
            if (lane >= off) x += y;
        }
        if (lane == 63) wsum[wv] = x;
        __syncthreads();
        if (t < 16) {
            int s = wsum[t], sx = s;
#pragma unroll
            for (int off = 1; off < 16; off <<= 1) {
                int y = __shfl_up(sx, off);
                if (t >= off) sx += y;
            }
            woff[t] = sx - s;
            if (t == 15) chunktot = sx;
        }
        __syncthreads();
        int excl = carry_s + woff[wv] + x - v;
        if (i < NN) { rowstart[i] = excl; cursor[i] = excl; }
        __syncthreads();
        if (t == 0) carry_s += chunktot;
        __syncthreads();
    }
    if (t == 0) rowstart[NN] = carry_s;
}

__global__ void k_fillv(int* __restrict__ esrc) {
    int i = blockIdx.x * 256 + threadIdx.x;
    if (i < EPAD) esrc[i] = NN;   // dummy node
}

__global__ void k_fill(const int* __restrict__ src, const int* __restrict__ dst,
                       int* __restrict__ cursor, int* __restrict__ esrc) {
    int e = blockIdx.x * 256 + threadIdx.x;
    if (e < NE) {
        int p = atomicAdd(&cursor[dst[e]], 1);
        esrc[p] = src[e];
    }
}

// ---------------- fused gather(+BN)+MFMA-GEMM1+stat partials ----------------
// FIRST: bf16 xb + packed mask. else: bf16 Z (node-major [n][r][64]) + BN-affine+ReLU.
// Block = 16 nodes = 64 rows; wave wv gathers its own 16-row strip, then MFMAs it.
template <bool FIRST>
__global__ __launch_bounds__(256) void k_fgg(const u16* __restrict__ Z,
                                             const u16* __restrict__ xb,
                                             const u32* __restrict__ m4,
                                             u16* __restrict__ Y,
                                             const int* __restrict__ rowstart,
                                             const int* __restrict__ esrc,
                                             const float* __restrict__ stats,
                                             const float* __restrict__ g,
                                             const float* __restrict__ b,
                                             const float* __restrict__ W,
                                             const float* __restrict__ bias,
                                             float* __restrict__ part) {
    __shared__ __align__(16) u16 Xs[64 * 64];
    __shared__ __align__(16) u16 Wt[64 * 64];
    __shared__ float red[4 * 128];
    const int t = threadIdx.x, lane = t & 63, wv = t >> 6;

    {   // stage Wt[n][k] = bf16(W[k][n]), swizzled (one-time scatter)
        int row = t >> 2, cb = (t & 3) * 16;
        const float* Wp = W + row * 64 + cb;
        float4 v0 = *(const float4*)Wp;
        float4 v1 = *(const float4*)(Wp + 4);
        float4 v2 = *(const float4*)(Wp + 8);
        float4 v3 = *(const float4*)(Wp + 12);
        float vv[16] = {v0.x, v0.y, v0.z, v0.w, v1.x, v1.y, v1.z, v1.w,
                        v2.x, v2.y, v2.z, v2.w, v3.x, v3.y, v3.z, v3.w};
#pragma unroll
        for (int j = 0; j < 16; j++) Wt[swz(cb + j, row * 2)] = f2bf(vv[j]);
    }
    __syncthreads();

    // ---- gather phase: lane covers (run rr, cols cl..cl+3) of a node row ----
    const int rr = lane >> 4;
    const int cl = (lane & 15) * 4;
    float sc[4] = {1.f, 1.f, 1.f, 1.f}, sh[4] = {0.f, 0.f, 0.f, 0.f};
    if (!FIRST) {
#pragma unroll
        for (int j = 0; j < 4; j++) {
            int c = cl + j;
            float m = stats[c] * (1.0f / MROWS);
            float var = stats[64 + c] * (1.0f / MROWS) - m * m;
            float rs = rsqrtf(var + BN_EPS);
            sc[j] = g[c] * rs;
            sh[j] = b[c] - m * sc[j];
        }
    }

#define LOADF(e, a0_, a1_, a2_, a3_)                                           \
    if (FIRST) {                                                               \
        u32 mb = m4[e];                                                        \
        ushort4 v = *(const ushort4*)(xb + (size_t)(e) * 64 + cl);             \
        bool keep = ((mb >> rr) & 1u) == 0u;                                   \
        a0_ = keep ? bf2f(v.x) : 0.f; a1_ = keep ? bf2f(v.y) : 0.f;            \
        a2_ = keep ? bf2f(v.z) : 0.f; a3_ = keep ? bf2f(v.w) : 0.f;            \
    } else {                                                                   \
        ushort4 v = *(const ushort4*)(Z + (size_t)(e) * 256 + lane * 4);       \
        bool real = (e) != NN;                                                 \
        a0_ = real ? fmaxf(fmaf(bf2f(v.x), sc[0], sh[0]), 0.f) : 0.f;          \
        a1_ = real ? fmaxf(fmaf(bf2f(v.y), sc[1], sh[1]), 0.f) : 0.f;          \
        a2_ = real ? fmaxf(fmaf(bf2f(v.z), sc[2], sh[2]), 0.f) : 0.f;          \
        a3_ = real ? fmaxf(fmaf(bf2f(v.w), sc[3], sh[3]), 0.f) : 0.f;          \
    }

    const int nbase = blockIdx.x * 16 + wv * 4;
#pragma unroll
    for (int i = 0; i < 4; i++) {
        const int n = nbase + i;
        float a0, a1, a2, a3;
        LOADF(n, a0, a1, a2, a3);
        int s0 = __builtin_amdgcn_readfirstlane(rowstart[n]);
        int s1 = __builtin_amdgcn_readfirstlane(rowstart[n + 1]);
        for (int k = s0; k < s1; k += 8) {   // padded: no tail
            int e0 = esrc[k], e1 = esrc[k + 1], e2 = esrc[k + 2], e3 = esrc[k + 3];
            int e4 = esrc[k + 4], e5 = esrc[k + 5], e6 = esrc[k + 6], e7 = esrc[k + 7];
            float b0, b1, b2, b3;
            LOADF(e0, b0, b1, b2, b3); a0 += b0; a1 += b1; a2 += b2; a3 += b3;
            LOADF(e1, b0, b1, b2, b3); a0 += b0; a1 += b1; a2 += b2; a3 += b3;
            LOADF(e2, b0, b1, b2, b3); a0 += b0; a1 += b1; a2 += b2; a3 += b3;
            LOADF(e3, b0, b1, b2, b3); a0 += b0; a1 += b1; a2 += b2; a3 += b3;
            LOADF(e4, b0, b1, b2, b3); a0 += b0; a1 += b1; a2 += b2; a3 += b3;
            LOADF(e5, b0, b1, b2, b3); a0 += b0; a1 += b1; a2 += b2; a3 += b3;
            LOADF(e6, b0, b1, b2, b3); a0 += b0; a1 += b1; a2 += b2; a3 += b3;
            LOADF(e7, b0, b1, b2, b3); a0 += b0; a1 += b1; a2 += b2; a3 += b3;
        }
        const int lrow = (wv * 4 + i) * 4 + rr;   // wave's own strip [16wv,16wv+16)
        u32 lo = (u32)f2bf(a0) | ((u32)f2bf(a1) << 16);
        u32 hi = (u32)f2bf(a2) | ((u32)f2bf(a3) << 16);
        *(uint2*)&Xs[swz(lrow, cl * 2)] = make_uint2(lo, hi);
    }
#undef LOADF

    // ---- MFMA phase: wave computes rows [16wv,16wv+16) x all 64 cols ----
    const int l15 = lane & 15, l4 = lane >> 4;
    const int arow = 16 * wv + l15;
    bf16x8 af0 = *(bf16x8*)&Xs[swz(arow, l4 * 16)];
    bf16x8 af1 = *(bf16x8*)&Xs[swz(arow, 64 + l4 * 16)];
    f32x4 acc[4];
#pragma unroll
    for (int n0 = 0; n0 < 4; n0++) {
        int n = n0 * 16 + l15;
        float bv = bias[n];
        acc[n0] = (f32x4){bv, bv, bv, bv};
        bf16x8 bf0 = *(bf16x8*)&Wt[swz(n, l4 * 16)];
        bf16x8 bf1 = *(bf16x8*)&Wt[swz(n, 64 + l4 * 16)];
        acc[n0] = __builtin_amdgcn_mfma_f32_16x16x32_bf16(af0, bf0, acc[n0], 0, 0, 0);
        acc[n0] = __builtin_amdgcn_mfma_f32_16x16x32_bf16(af1, bf1, acc[n0], 0, 0, 0);
    }

    const int m0 = blockIdx.x * 64;
#pragma unroll
    for (int n0 = 0; n0 < 4; n0++) {
        int col = n0 * 16 + l15;
#pragma unroll
        for (int j = 0; j < 4; j++) {
            int row = 16 * wv + l4 * 4 + j;
            Y[(size_t)(m0 + row) * 64 + col] = f2bf(acc[n0][j]);
        }
    }

    // stats partials
#pragma unroll
    for (int n0 = 0; n0 < 4; n0++) {
        float s = acc[n0][0] + acc[n0][1] + acc[n0][2] + acc[n0][3];
        float q = acc[n0][0] * acc[n0][0] + acc[n0][1] * acc[n0][1] +
                  acc[n0][2] * acc[n0][2] + acc[n0][3] * acc[n0][3];
        s += __shfl_xor(s, 16); s += __shfl_xor(s, 32);
        q += __shfl_xor(q, 16); q += __shfl_xor(q, 32);
        if (l4 == 0) {
            red[wv * 128 + n0 * 16 + l15] = s;
            red[wv * 128 + 64 + n0 * 16 + l15] = q;
        }
    }
    __syncthreads();
    if (t < 128) {
        float v = red[t] + red[128 + t] + red[256 + t] + red[384 + t];
        part[(size_t)t * NBLK + blockIdx.x] = v;
    }
}

// ---------------- GEMM2: bf16 in/out, input BN+ReLU, MFMA, stat partials ----------------
__global__ __launch_bounds__(256) void k_gemm(const u16* __restrict__ X,
                                              u16* __restrict__ Y,
                                              const float* __restrict__ W,
                                              const float* __restrict__ bias,
                                              const float* __restrict__ inStats,
                                              const float* __restrict__ gamma,
                                              const float* __restrict__ beta,
                                              float* __restrict__ part) {
    __shared__ __align__(16) u16 Xs[64 * 64];
    __shared__ __align__(16) u16 Wt[64 * 64];
    __shared__ float red[4 * 128];
    __shared__ float Pm[64], Pr[64], Pg[64], Pb[64];
    const int t = threadIdx.x, lane = t & 63, wv = t >> 6;

    {   // stage Wt
        int row = t >> 2, cb = (t & 3) * 16;
        const float* Wp = W + row * 64 + cb;
        float4 v0 = *(const float4*)Wp;
        float4 v1 = *(const float4*)(Wp + 4);
        float4 v2 = *(const float4*)(Wp + 8);
        float4 v3 = *(const float4*)(Wp + 12);
        float vv[16] = {v0.x, v0.y, v0.z, v0.w, v1.x, v1.y, v1.z, v1.w,
                        v2.x, v2.y, v2.z, v2.w, v3.x, v3.y, v3.z, v3.w};
#pragma unroll
        for (int j = 0; j < 16; j++) Wt[swz(cb + j, row * 2)] = f2bf(vv[j]);
    }
    if (t < 64) {
        float m = inStats[t] * (1.0f / MROWS);
        float var = inStats[64 + t] * (1.0f / MROWS) - m * m;
        Pm[t] = m;
        Pr[t] = rsqrtf(var + BN_EPS);
        Pg[t] = gamma[t];
        Pb[t] = beta[t];
    }
    __syncthreads();

    const int row = t >> 2, cb = (t & 3) * 16;
    const int m0 = blockIdx.x * 64;
    {   // stage X rows (own-wave strip), BN+ReLU, bf16, swizzled
        const u16* Xp = X + (size_t)(m0 + row) * 64 + cb;
        uint4 a = *(const uint4*)Xp;
        uint4 bq = *(const uint4*)(Xp + 8);
        u32 w[8] = {a.x, a.y, a.z, a.w, bq.x, bq.y, bq.z, bq.w};
        u32 ow[8];
#pragma unroll
        for (int j = 0; j < 8; j++) {
            int c = cb + 2 * j;
            union { u32 u; float f; } lo, hi;
            lo.u = w[j] << 16;
            hi.u = w[j] & 0xffff0000u;
            float v0 = fmaxf(fmaf((lo.f - Pm[c]) * Pr[c], Pg[c], Pb[c]), 0.f);
            float v1 = fmaxf(fmaf((hi.f - Pm[c + 1]) * Pr[c + 1], Pg[c + 1], Pb[c + 1]), 0.f);
            ow[j] = (u32)f2bf(v0) | ((u32)f2bf(v1) << 16);
        }
        *(uint4*)&Xs[swz(row, cb * 2)] = make_uint4(ow[0], ow[1], ow[2], ow[3]);
        *(uint4*)&Xs[swz(row, cb * 2 + 16)] = make_uint4(ow[4], ow[5], ow[6], ow[7]);
    }

    const int l15 = lane & 15, l4 = lane >> 4;
    const int arow = 16 * wv + l15;
    bf16x8 af0 = *(bf16x8*)&Xs[swz(arow, l4 * 16)];
    bf16x8 af1 = *(bf16x8*)&Xs[swz(arow, 64 + l4 * 16)];
    f32x4 acc[4];
#pragma unroll
    for (int n0 = 0; n0 < 4; n0++) {
        int n = n0 * 16 + l15;
        float bv = bias[n];
        acc[n0] = (f32x4){bv, bv, bv, bv};
        bf16x8 bf0 = *(bf16x8*)&Wt[swz(n, l4 * 16)];
        bf16x8 bf1 = *(bf16x8*)&Wt[swz(n, 64 + l4 * 16)];
        acc[n0] = __builtin_amdgcn_mfma_f32_16x16x32_bf16(af0, bf0, acc[n0], 0, 0, 0);
        acc[n0] = __builtin_amdgcn_mfma_f32_16x16x32_bf16(af1, bf1, acc[n0], 0, 0, 0);
    }

#pragma unroll
    for (int n0 = 0; n0 < 4; n0++) {
        int col = n0 * 16 + l15;
#pragma unroll
        for (int j = 0; j < 4; j++) {
            int r2 = 16 * wv + l4 * 4 + j;
            Y[(size_t)(m0 + r2) * 64 + col] = f2bf(acc[n0][j]);
        }
    }

#pragma unroll
    for (int n0 = 0; n0 < 4; n0++) {
        float s = acc[n0][0] + acc[n0][1] + acc[n0][2] + acc[n0][3];
        float q = acc[n0][0] * acc[n0][0] + acc[n0][1] * acc[n0][1] +
                  acc[n0][2] * acc[n0][2] + acc[n0][3] * acc[n0][3];
        s += __shfl_xor(s, 16); s += __shfl_xor(s, 32);
        q += __shfl_xor(q, 16); q += __shfl_xor(q, 32);
        if (l4 == 0) {
            red[wv * 128 + n0 * 16 + l15] = s;
            red[wv * 128 + 64 + n0 * 16 + l15] = q;
        }
    }
    __syncthreads();
    if (t < 128) {
        float v = red[t] + red[128 + t] + red[256 + t] + red[384 + t];
        part[(size_t)t * NBLK + blockIdx.x] = v;
    }
}

// ---------------- reduce stat partials ----------------
__global__ __launch_bounds__(256) void k_statreduce(const float* __restrict__ part,
                                                    float* __restrict__ stats) {
    const int j = blockIdx.x;
    const int t = threadIdx.x;
    float s = 0.f;
    for (int p = t; p < NBLK; p += 256) s += part[(size_t)j * NBLK + p];
#pragma unroll
    for (int off = 32; off > 0; off >>= 1) s += __shfl_xor(s, off);
    __shared__ float red[4];
    if ((t & 63) == 0) red[t >> 6] = s;
    __syncthreads();
    if (t == 0) stats[j] = red[0] + red[1] + red[2] + red[3];
}

// ---------------- segmented pooling with fused BN-affine+ReLU ----------------
__global__ __launch_bounds__(256) void k_pool(const u16* __restrict__ Z,
                                              const int* __restrict__ batch,
                                              float* __restrict__ pooled,
                                              const float* __restrict__ stats,
                                              const float* __restrict__ g,
                                              const float* __restrict__ b) {
    const int gr = blockIdx.x;
    const int t = threadIdx.x;
    int lo = 0, hi = NN;
    while (lo < hi) { int mid = (lo + hi) >> 1; if (batch[mid] < gr) lo = mid + 1; else hi = mid; }
    const int start = lo;
    lo = 0; hi = NN;
    while (lo < hi) { int mid = (lo + hi) >> 1; if (batch[mid] < gr + 1) lo = mid + 1; else hi = mid; }
    const int end = lo;

    const int l = t & 63, w = t >> 6;
    const int c0 = (l * 4) & 63;
    float sc[4], sh[4];
#pragma unroll
    for (int j = 0; j < 4; j++) {
        int c = c0 + j;
        float m = stats[c] * (1.0f / MROWS);
        float var = stats[64 + c] * (1.0f / MROWS) - m * m;
        float rs = rsqrtf(var + BN_EPS);
        sc[j] = g[c] * rs;
        sh[j] = b[c] - m * sc[j];
    }
    float a0 = 0.f, a1 = 0.f, a2 = 0.f, a3 = 0.f;
#define PBODY(nn)                                                              \
    {                                                                          \
        ushort4 v = *(const ushort4*)(Z + (size_t)(nn) * 256 + l * 4);         \
        a0 += fmaxf(fmaf(bf2f(v.x), sc[0], sh[0]), 0.f);                       \
        a1 += fmaxf(fmaf(bf2f(v.y), sc[1], sh[1]), 0.f);                       \
        a2 += fmaxf(fmaf(bf2f(v.z), sc[2], sh[2]), 0.f);                       \
        a3 += fmaxf(fmaf(bf2f(v.w), sc[3], sh[3]), 0.f);                       \
    }
    int n = start + w;
    for (; n + 12 < end; n += 16) { PBODY(n); PBODY(n + 4); PBODY(n + 8); PBODY(n + 12); }
    for (; n < end; n += 4) PBODY(n);
#undef PBODY
    __shared__ float red[256][4];
    red[t][0] = a0; red[t][1] = a1; red[t][2] = a2; red[t][3] = a3;
    __syncthreads();
    if (t < 64) {
        float s = 0.f;
#pragma unroll
        for (int w2 = 0; w2 < 4; w2++)
#pragma unroll
            for (int r = 0; r < 4; r++)
                s += red[w2 * 64 + r * 16 + (t >> 2)][t & 3];
        pooled[gr * D + t] = 0.25f * s;
    }
}

// ---------------- readout ----------------
__global__ __launch_bounds__(256) void k_readout(const float* __restrict__ pooled,
                                                 const float* __restrict__ fcW,
                                                 const float* __restrict__ fcb,
                                                 float* __restrict__ out) {
    const int gr = blockIdx.x, t = threadIdx.x;
    const int c = t & 15, seg = t >> 4;
    float acc = 0.f;
#pragma unroll
    for (int i = 0; i < 5; i++)
#pragma unroll
        for (int k = 0; k < 4; k++) {
            int d = seg * 4 + k;
            acc = fmaf(pooled[i * (NG * D) + gr * D + d], fcW[i * 1024 + d * 16 + c], acc);
        }
    __shared__ float red[16][17];
    red[seg][c] = acc;
    __syncthreads();
    if (t < 16) {
        float s = 0.f;
#pragma unroll
        for (int s2 = 0; s2 < 16; s2++) s += red[s2][t];
#pragma unroll
        for (int i = 0; i < 5; i++) s += fcb[i * NC + t];
        float mx = s;
#pragma unroll
        for (int m = 1; m < 16; m <<= 1) mx = fmaxf(mx, __shfl_xor(mx, m));
        float e = expf(s - mx), se = e;
#pragma unroll
        for (int m = 1; m < 16; m <<= 1) se += __shfl_xor(se, m);
        out[gr * NC + t] = s - mx - logf(se);
    }
}

extern "C" void kernel_launch(void* const* d_in, const int* in_sizes, int n_in,
                              void* d_out, int out_size, void* d_ws, size_t ws_size,
                              hipStream_t stream) {
    const float* x = (const float*)d_in[0];
    const int* ei = (const int*)d_in[1];
    const int* srcp = ei;
    const int* dstp = ei + NE;
    const int* batch = (const int*)d_in[2];
    const int* mask = (const int*)d_in[3];
    const float* convW1 = (const float*)d_in[4];
    const float* convb1 = (const float*)d_in[5];
    const float* mlp_bn_g = (const float*)d_in[6];
    const float* mlp_bn_b = (const float*)d_in[7];
    const float* convW2 = (const float*)d_in[8];
    const float* convb2 = (const float*)d_in[9];
    const float* bn_g = (const float*)d_in[10];
    const float* bn_b = (const float*)d_in[11];
    const float* fcW = (const float*)d_in[12];
    const float* fcb = (const float*)d_in[13];
    float* out = (float*)d_out;

    u16* P = (u16*)d_ws;                               // [NN][256] bf16
    u16* Q = P + (size_t)NN * 256;                     // [NN+1][256] bf16 (dummy row, predicated off)
    u16* xb = Q + (size_t)(NN + 1) * 256;              // [NN+1][64] bf16
    float* pooled = (float*)(xb + (size_t)(NN + 1) * 64);  // [5][NG][D]
    float* stats = pooled + 5 * NG * D;                // [NL][2][128]
    float* part = stats + NL * 2 * 128;                // [128][NBLK]
    u32* m4 = (u32*)(part + 128 * NBLK);               // [NN+1]
    int* deg = (int*)(m4 + NN + 1);                    // [NN]
    int* rowstart = deg + NN;                          // [NN+1]
    int* cursor = rowstart + NN + 1;                   // [NN]
    int* esrc = cursor + NN;                           // [EPAD]

    k_zero<<<(NN + 255) / 256, 256, 0, stream>>>(deg, NN);
    k_maskpack<<<(NN + 256) / 256, 256, 0, stream>>>(mask, m4);
    k_prep<<<((NN + 1) * 16 + 255) / 256, 256, 0, stream>>>(x, xb);
    k_pool0<<<NG, 256, 0, stream>>>(x, m4, batch, pooled);

    k_deg<<<(NE + 255) / 256, 256, 0, stream>>>(dstp, deg);
    k_scan<<<1, 1024, 0, stream>>>(deg, rowstart, cursor);
    k_fillv<<<(EPAD + 255) / 256, 256, 0, stream>>>(esrc);
    k_fill<<<(NE + 255) / 256, 256, 0, stream>>>(srcp, dstp, cursor, esrc);

    for (int i = 0; i < NL; i++) {
        float* st1 = stats + (i * 2 + 0) * 128;
        float* st2 = stats + (i * 2 + 1) * 128;
        if (i == 0)
            k_fgg<true><<<NBLK, 256, 0, stream>>>(nullptr, xb, m4, P, rowstart, esrc,
                                                  nullptr, nullptr, nullptr,
                                                  convW1, convb1, part);
        else
            k_fgg<false><<<NBLK, 256, 0, stream>>>(Q, nullptr, nullptr, P, rowstart, esrc,
                                                   stats + ((i - 1) * 2 + 1) * 128,
                                                   bn_g + (i - 1) * 64, bn_b + (i - 1) * 64,
                                                   convW1 + i * 4096, convb1 + i * 64, part);
        k_statreduce<<<128, 256, 0, stream>>>(part, st1);
        k_gemm<<<NBLK, 256, 0, stream>>>(P, Q, convW2 + i * 4096, convb2 + i * 64,
                                         st1, mlp_bn_g + i * 64, mlp_bn_b + i * 64, part);
        k_statreduce<<<128, 256, 0, stream>>>(part, st2);
        k_pool<<<NG, 256, 0, stream>>>(Q, batch, pooled + (i + 1) * (NG * D),
                                       st2, bn_g + i * 64, bn_b + i * 64);
    }

    k_readout<<<NG, 256, 0, stream>>>(pooled, fcW, fcb, out);
}